// Round 1
// baseline (240.475 us; speedup 1.0000x reference)
//
#include <hip/hip_runtime.h>
#include <stdint.h>

typedef unsigned short ushort_t;
typedef __attribute__((ext_vector_type(8))) short short8;
typedef __attribute__((ext_vector_type(4))) float f32x4;
typedef __attribute__((ext_vector_type(4))) unsigned short ushort4v;

#define NBATCH 32
#define SEQ 1024
#define DIM 256
#define NH 8
#define ROWS (NBATCH * SEQ)   // 32768

__device__ __forceinline__ ushort_t f2bf(float f) {
    uint32_t u = __float_as_uint(f);
    u += 0x7fffu + ((u >> 16) & 1u);   // round-to-nearest-even
    return (ushort_t)(u >> 16);
}
__device__ __forceinline__ float bf2f(ushort_t h) {
    return __uint_as_float(((uint32_t)h) << 16);
}

typedef __attribute__((address_space(3))) void lds_void_t;
typedef const __attribute__((address_space(1))) void glob_void_t;
__device__ __forceinline__ void gld_lds16(const void* g, void* l) {
    __builtin_amdgcn_global_load_lds((glob_void_t*)g, (lds_void_t*)l, 16, 0, 0);
}

// ---------------------------------------------------------------------------
// Kernel 1: weight prep — wT[n][k] = (bf16) w[k][n] for wq|wk|wv packed, wf1, wf2
// ---------------------------------------------------------------------------
__global__ __launch_bounds__(256) void prep_weights(
    const float* __restrict__ wq, const float* __restrict__ wk,
    const float* __restrict__ wv, const float* __restrict__ wf1,
    const float* __restrict__ wf2, ushort_t* __restrict__ wqkvT,
    ushort_t* __restrict__ wf1T, ushort_t* __restrict__ wf2T) {
    int n = blockIdx.x;
    int k = threadIdx.x;
    if (n < 768) {
        const float* w = (n < 256) ? wq : (n < 512 ? wk : wv);
        int nn = n & 255;
        wqkvT[n * 256 + k] = f2bf(w[k * 256 + nn]);
    } else if (n < 1024) {
        int nn = n - 768;
        wf1T[nn * 256 + k] = f2bf(wf1[k * 256 + nn]);
    } else {
        int nn = n - 1024;
        wf2T[nn * 256 + k] = f2bf(wf2[k * 256 + nn]);
    }
}

// ---------------------------------------------------------------------------
// Kernel 2/6: LayerNorm (one wave per 256-elem row), optional +ctx residual
// ---------------------------------------------------------------------------
template <int ADD_CTX>
__global__ __launch_bounds__(256) void ln_kernel(
    const float* __restrict__ x, const ushort_t* __restrict__ ctx,
    const float* __restrict__ g, const float* __restrict__ beta,
    ushort_t* __restrict__ out) {
    int wid = threadIdx.x >> 6, lane = threadIdx.x & 63;
    size_t row = (size_t)blockIdx.x * 4 + wid;
    size_t base = row * 256 + lane * 4;
    float4 v = *(const float4*)(x + base);
    if (ADD_CTX) {
        ushort4v c = *(const ushort4v*)(ctx + base);
        v.x += bf2f(c[0]); v.y += bf2f(c[1]);
        v.z += bf2f(c[2]); v.w += bf2f(c[3]);
    }
    float s  = v.x + v.y + v.z + v.w;
    float s2 = v.x * v.x + v.y * v.y + v.z * v.z + v.w * v.w;
#pragma unroll
    for (int msk = 1; msk < 64; msk <<= 1) {
        s  += __shfl_xor(s, msk);
        s2 += __shfl_xor(s2, msk);
    }
    float mu  = s * (1.f / 256.f);
    float var = s2 * (1.f / 256.f) - mu * mu;
    float rs  = rsqrtf(var + 1e-5f);
    const float4 gv = *(const float4*)(g + lane * 4);
    const float4 bv = *(const float4*)(beta + lane * 4);
    ushort4v o;
    o[0] = f2bf((v.x - mu) * rs * gv.x + bv.x);
    o[1] = f2bf((v.y - mu) * rs * gv.y + bv.y);
    o[2] = f2bf((v.z - mu) * rs * gv.z + bv.z);
    o[3] = f2bf((v.w - mu) * rs * gv.w + bv.w);
    *(ushort4v*)(out + base) = o;
}

// ---------------------------------------------------------------------------
// Kernels 3/7/8: GEMM C[M x N] = A[M x 256] @ B^T[N x 256]^T   (bf16, fp32 acc)
// 128x128 tile, BK=32, 4 waves (2x2), 4x4 16x16x32 MFMA frags per wave.
// EPI: 0 = plain -> bf16 C     (QKV, ldc=768)
//      1 = +bias, relu -> bf16 (FFN1, ldc=256)
//      2 = +bias, +res -> f32  (FFN2 -> d_out, ldc=256)
// ---------------------------------------------------------------------------
template <int EPI>
__global__ __launch_bounds__(256) void gemm_bt(
    const ushort_t* __restrict__ A, const ushort_t* __restrict__ B,
    void* __restrict__ Cp, const float* __restrict__ bias,
    const ushort_t* __restrict__ res, int nbn, int ldc) {
    __shared__ ushort_t lds_a[4096];  // [128][32]
    __shared__ ushort_t lds_b[4096];  // [128][32] (rows = output cols)
    int blk = blockIdx.x;
    int bn = blk % nbn, bm = blk / nbn;
    int m0 = bm * 128, n0 = bn * 128;
    int tid = threadIdx.x, wid = tid >> 6, lane = tid & 63;
    int fr = lane & 15, g = lane >> 4;
    int wm = (wid >> 1) * 64, wn = (wid & 1) * 64;

    f32x4 acc[4][4];
    const f32x4 fz = {0.f, 0.f, 0.f, 0.f};
#pragma unroll
    for (int m = 0; m < 4; m++)
#pragma unroll
        for (int n = 0; n < 4; n++) acc[m][n] = fz;

    for (int kt = 0; kt < 256; kt += 32) {
#pragma unroll
        for (int i = 0; i < 2; i++) {
            const ushort_t* as =
                A + (size_t)(m0 + i * 64 + (tid >> 2)) * 256 + kt + (tid & 3) * 8;
            gld_lds16(as, &lds_a[i * 2048 + wid * 512]);
            const ushort_t* bs =
                B + (size_t)(n0 + i * 64 + (tid >> 2)) * 256 + kt + (tid & 3) * 8;
            gld_lds16(bs, &lds_b[i * 2048 + wid * 512]);
        }
        __syncthreads();
        short8 af[4], bfr[4];
#pragma unroll
        for (int m = 0; m < 4; m++)
            af[m] = *(const short8*)&lds_a[(wm + m * 16 + fr) * 32 + g * 8];
#pragma unroll
        for (int n = 0; n < 4; n++)
            bfr[n] = *(const short8*)&lds_b[(wn + n * 16 + fr) * 32 + g * 8];
#pragma unroll
        for (int m = 0; m < 4; m++)
#pragma unroll
            for (int n = 0; n < 4; n++)
                acc[m][n] = __builtin_amdgcn_mfma_f32_16x16x32_bf16(
                    af[m], bfr[n], acc[m][n], 0, 0, 0);
        __syncthreads();
    }

#pragma unroll
    for (int m = 0; m < 4; m++)
#pragma unroll
        for (int n = 0; n < 4; n++) {
            int col = n0 + wn + n * 16 + fr;
            float bv = (EPI >= 1) ? bias[col] : 0.f;
#pragma unroll
            for (int j = 0; j < 4; j++) {
                size_t row = (size_t)(m0 + wm + m * 16 + g * 4 + j);
                float v = acc[m][n][j] + bv;
                if (EPI == 1) v = fmaxf(v, 0.f);
                if (EPI == 2) {
                    v += bf2f(res[row * 256 + col]);
                    ((float*)Cp)[row * ldc + col] = v;
                } else {
                    ((ushort_t*)Cp)[row * ldc + col] = f2bf(v);
                }
            }
        }
}

// ---------------------------------------------------------------------------
// Kernel 4: V transpose  v[b,s,h,hd] (in qkv cols 512..767) -> vt[bh][hd][s]
// ---------------------------------------------------------------------------
__global__ __launch_bounds__(256) void vtrans(const ushort_t* __restrict__ qkv,
                                              ushort_t* __restrict__ vt) {
    __shared__ ushort_t tile[128][40];  // 80B rows: 16B aligned, conflict-broken
    int bh = blockIdx.x >> 3, sb = blockIdx.x & 7;
    int b = bh >> 3, h = bh & 7;
    int t = threadIdx.x;
    int s0 = sb * 128;
#pragma unroll
    for (int i = 0; i < 2; i++) {
        int s = i * 64 + (t >> 2);
        int hd0 = (t & 3) * 8;
        short8 v = *(const short8*)(qkv + ((size_t)b * SEQ + s0 + s) * 768 + 512 +
                                    h * 32 + hd0);
        *(short8*)&tile[s][hd0] = v;
    }
    __syncthreads();
    int hd = t >> 3, c0 = (t & 7) * 16;
    short8 o0, o1;
#pragma unroll
    for (int i = 0; i < 8; i++) o0[i] = (short)tile[c0 + i][hd];
#pragma unroll
    for (int i = 0; i < 8; i++) o1[i] = (short)tile[c0 + 8 + i][hd];
    ushort_t* dst = vt + (size_t)bh * 32768 + (size_t)hd * 1024 + s0 + c0;
    *(short8*)dst = o0;
    *(short8*)(dst + 8) = o1;
}

// ---------------------------------------------------------------------------
// Kernel 5: flash attention (no 1/sqrt(d) scaling, per reference).
// Block = (b,h) x 128 Q-rows; 4 waves x 32 rows; KVBLK=128.
// K tile [128][32] and V^T tile [32][128] staged via global_load_lds with
// both-sides XOR swizzle; P transposed through padded per-wave LDS.
// ---------------------------------------------------------------------------
__global__ __launch_bounds__(256) void attn_kernel(
    const ushort_t* __restrict__ qkv, const ushort_t* __restrict__ vt,
    ushort_t* __restrict__ ctx) {
    __shared__ ushort_t k_lds[4096];      // [128 keys][32 hd], swizzled
    __shared__ ushort_t v_lds[4096];      // [32 hd][128 keys], swizzled
    __shared__ ushort_t p_lds[4 * 4352];  // per-wave [32][136]
    int bh = blockIdx.x >> 3, qt = blockIdx.x & 7;
    int b = bh >> 3, h = bh & 7;
    int tid = threadIdx.x, wid = tid >> 6, lane = tid & 63;
    int fr = lane & 15, g = lane >> 4;
    int q0 = qt * 128 + wid * 32;

    // Q fragments straight from global (row stride 768 elems)
    short8 qa[2];
#pragma unroll
    for (int m = 0; m < 2; m++) {
        size_t row = (size_t)b * SEQ + q0 + m * 16 + fr;
        qa[m] = *(const short8*)(qkv + row * 768 + h * 32 + g * 8);
    }
    f32x4 acc[2][2];
    const f32x4 fz = {0.f, 0.f, 0.f, 0.f};
#pragma unroll
    for (int m = 0; m < 2; m++)
#pragma unroll
        for (int n = 0; n < 2; n++) acc[m][n] = fz;
    float mrun[2][4], lrun[2][4];
#pragma unroll
    for (int m = 0; m < 2; m++)
#pragma unroll
        for (int j = 0; j < 4; j++) {
            mrun[m][j] = -1e30f;
            lrun[m][j] = 0.f;
        }

    ushort_t* pw = &p_lds[wid * 4352];
    const int t = tid;

    for (int kv = 0; kv < SEQ; kv += 128) {
        // ---- stage K and V^T tiles (pre-swizzled global source, linear LDS dest)
#pragma unroll
        for (int i = 0; i < 2; i++) {
            int krow = i * 64 + (t >> 2);
            int kslot = (t & 3) ^ ((t >> 3) & 3);
            const ushort_t* ks = qkv + ((size_t)b * SEQ + kv + krow) * 768 + 256 +
                                 h * 32 + kslot * 8;
            gld_lds16(ks, &k_lds[i * 2048 + wid * 512]);
            int hd = i * 16 + (t >> 4);
            int vslot = (t & 15) ^ (hd & 7);
            const ushort_t* vs =
                vt + (size_t)bh * 32768 + (size_t)hd * 1024 + kv + vslot * 8;
            gld_lds16(vs, &v_lds[i * 2048 + wid * 512]);
        }
        __syncthreads();

        // ---- scores: S = Q @ K^T  (K tile read as B^T, swizzled)
        short8 kb[8];
#pragma unroll
        for (int n = 0; n < 8; n++) {
            int row = n * 16 + fr;
            int off = row * 64 + ((g ^ ((fr >> 1) & 3)) << 4);
            kb[n] = *(const short8*)((const char*)k_lds + off);
        }
        f32x4 s[2][8];
#pragma unroll
        for (int m = 0; m < 2; m++)
#pragma unroll
            for (int n = 0; n < 8; n++)
                s[m][n] = __builtin_amdgcn_mfma_f32_16x16x32_bf16(qa[m], kb[n], fz,
                                                                  0, 0, 0);

        // ---- online softmax (rows replicated across the 16 fr-lanes)
#pragma unroll
        for (int m = 0; m < 2; m++) {
#pragma unroll
            for (int j = 0; j < 4; j++) {
                float mx = s[m][0][j];
#pragma unroll
                for (int n = 1; n < 8; n++) mx = fmaxf(mx, s[m][n][j]);
                mx = fmaxf(mx, __shfl_xor(mx, 1));
                mx = fmaxf(mx, __shfl_xor(mx, 2));
                mx = fmaxf(mx, __shfl_xor(mx, 4));
                mx = fmaxf(mx, __shfl_xor(mx, 8));
                float mnew = fmaxf(mrun[m][j], mx);
                float scl = __expf(mrun[m][j] - mnew);
                float sum = 0.f;
#pragma unroll
                for (int n = 0; n < 8; n++) {
                    float p = __expf(s[m][n][j] - mnew);
                    s[m][n][j] = p;
                    sum += p;
                }
                sum += __shfl_xor(sum, 1);
                sum += __shfl_xor(sum, 2);
                sum += __shfl_xor(sum, 4);
                sum += __shfl_xor(sum, 8);
                mrun[m][j] = mnew;
                lrun[m][j] = lrun[m][j] * scl + sum;
                acc[m][0][j] *= scl;
                acc[m][1][j] *= scl;
            }
        }

        // ---- P -> per-wave LDS (D-layout scatter, padded rows: 2-way max)
#pragma unroll
        for (int m = 0; m < 2; m++)
#pragma unroll
            for (int n = 0; n < 8; n++)
#pragma unroll
                for (int j = 0; j < 4; j++)
                    pw[(m * 16 + g * 4 + j) * 136 + n * 16 + fr] =
                        f2bf(s[m][n][j]);

        // ---- PV: ctx += P @ V   (A = P from LDS, B^T = V^T tile, swizzled)
#pragma unroll
        for (int kk = 0; kk < 4; kk++) {
            short8 pa[2];
#pragma unroll
            for (int m = 0; m < 2; m++)
                pa[m] = *(const short8*)&pw[(m * 16 + fr) * 136 + kk * 32 + g * 8];
#pragma unroll
            for (int n = 0; n < 2; n++) {
                int vrow = n * 16 + fr;
                int voff = vrow * 256 + ((kk * 64 + g * 16) ^ ((fr & 7) << 4));
                short8 vb = *(const short8*)((const char*)v_lds + voff);
#pragma unroll
                for (int m = 0; m < 2; m++)
                    acc[m][n] = __builtin_amdgcn_mfma_f32_16x16x32_bf16(
                        pa[m], vb, acc[m][n], 0, 0, 0);
            }
        }
        __syncthreads();
    }

    // ---- epilogue: ctx = acc / l
#pragma unroll
    for (int m = 0; m < 2; m++)
#pragma unroll
        for (int n = 0; n < 2; n++)
#pragma unroll
            for (int j = 0; j < 4; j++) {
                float v = acc[m][n][j] / lrun[m][j];
                size_t row = (size_t)b * SEQ + q0 + m * 16 + g * 4 + j;
                ctx[row * 256 + h * 32 + n * 16 + fr] = f2bf(v);
            }
}

// ---------------------------------------------------------------------------
extern "C" void kernel_launch(void* const* d_in, const int* in_sizes, int n_in,
                              void* d_out, int out_size, void* d_ws,
                              size_t ws_size, hipStream_t stream) {
    const float* x   = (const float*)d_in[0];
    const float* wq  = (const float*)d_in[1];
    const float* wk  = (const float*)d_in[2];
    const float* wv  = (const float*)d_in[3];
    const float* g1  = (const float*)d_in[4];
    const float* be1 = (const float*)d_in[5];
    const float* g2  = (const float*)d_in[6];
    const float* be2 = (const float*)d_in[7];
    const float* wf1 = (const float*)d_in[8];
    const float* bf1 = (const float*)d_in[9];
    const float* wf2 = (const float*)d_in[10];
    const float* bf2 = (const float*)d_in[11];

    char* ws = (char*)d_ws;
    const size_t SZ16M = (size_t)ROWS * 256 * 2;  // 16 MiB
    ushort_t* wqkvT = (ushort_t*)(ws);                      // 768*256*2
    ushort_t* wf1T  = (ushort_t*)(ws + 393216);
    ushort_t* wf2T  = (ushort_t*)(ws + 524288);
    ushort_t* xn    = (ushort_t*)(ws + 655360);             // 16 MiB (reused as h)
    ushort_t* qkvb  = (ushort_t*)(ws + 655360 + SZ16M);     // 48 MiB
    ushort_t* vtb   = (ushort_t*)(ws + 655360 + SZ16M + (size_t)ROWS * 768 * 2);
    ushort_t* ctxb  = (ushort_t*)((char*)vtb + SZ16M);
    ushort_t* ab    = (ushort_t*)((char*)ctxb + SZ16M);
    ushort_t* hb    = xn;  // xn dead after QKV GEMM

    prep_weights<<<dim3(1280), dim3(256), 0, stream>>>(wq, wk, wv, wf1, wf2,
                                                       wqkvT, wf1T, wf2T);
    ln_kernel<0><<<dim3(ROWS / 4), dim3(256), 0, stream>>>(x, nullptr, g1, be1,
                                                           xn);
    gemm_bt<0><<<dim3(256 * 6), dim3(256), 0, stream>>>(xn, wqkvT, (void*)qkvb,
                                                        nullptr, nullptr, 6, 768);
    vtrans<<<dim3(2048), dim3(256), 0, stream>>>(qkvb, vtb);
    attn_kernel<<<dim3(2048), dim3(256), 0, stream>>>(qkvb, vtb, ctxb);
    ln_kernel<1><<<dim3(ROWS / 4), dim3(256), 0, stream>>>(x, ctxb, g2, be2, ab);
    gemm_bt<1><<<dim3(256 * 2), dim3(256), 0, stream>>>(ab, wf1T, (void*)hb, bf1,
                                                        nullptr, 2, 256);
    gemm_bt<2><<<dim3(256 * 2), dim3(256), 0, stream>>>(hb, wf2T, d_out, bf2, ab,
                                                        2, 256);
}

// Round 2
// 235.518 us; speedup vs baseline: 1.0210x; 1.0210x over previous
//
#include <hip/hip_runtime.h>
#include <stdint.h>

typedef unsigned short ushort_t;
typedef __attribute__((ext_vector_type(8))) short short8;
typedef __attribute__((ext_vector_type(4))) float f32x4;
typedef __attribute__((ext_vector_type(4))) unsigned short ushort4v;

#define NBATCH 32
#define SEQ 1024
#define DIM 256
#define NH 8
#define ROWS (NBATCH * SEQ)   // 32768

__device__ __forceinline__ ushort_t f2bf(float f) {
    uint32_t u = __float_as_uint(f);
    u += 0x7fffu + ((u >> 16) & 1u);   // round-to-nearest-even
    return (ushort_t)(u >> 16);
}
__device__ __forceinline__ float bf2f(ushort_t h) {
    return __uint_as_float(((uint32_t)h) << 16);
}
__device__ __forceinline__ float exp2_fast(float x) {
    float r;
    asm("v_exp_f32 %0, %1" : "=v"(r) : "v"(x));
    return r;
}

typedef __attribute__((address_space(3))) void lds_void_t;
typedef const __attribute__((address_space(1))) void glob_void_t;
__device__ __forceinline__ void gld_lds16(const void* g, void* l) {
    __builtin_amdgcn_global_load_lds((glob_void_t*)g, (lds_void_t*)l, 16, 0, 0);
}

// ---------------------------------------------------------------------------
// Kernel 1: weight prep — wT[n][k] = (bf16) w[k][n] for wq|wk|wv packed, wf1, wf2
// wq additionally scaled by log2(e): attention softmax runs in exp2 domain.
// ---------------------------------------------------------------------------
__global__ __launch_bounds__(256) void prep_weights(
    const float* __restrict__ wq, const float* __restrict__ wk,
    const float* __restrict__ wv, const float* __restrict__ wf1,
    const float* __restrict__ wf2, ushort_t* __restrict__ wqkvT,
    ushort_t* __restrict__ wf1T, ushort_t* __restrict__ wf2T) {
    int n = blockIdx.x;
    int k = threadIdx.x;
    if (n < 768) {
        const float* w = (n < 256) ? wq : (n < 512 ? wk : wv);
        int nn = n & 255;
        float v = w[k * 256 + nn];
        if (n < 256) v *= 1.4426950408889634f;  // log2(e) fold for exp2 softmax
        wqkvT[n * 256 + k] = f2bf(v);
    } else if (n < 1024) {
        int nn = n - 768;
        wf1T[nn * 256 + k] = f2bf(wf1[k * 256 + nn]);
    } else {
        int nn = n - 1024;
        wf2T[nn * 256 + k] = f2bf(wf2[k * 256 + nn]);
    }
}

// ---------------------------------------------------------------------------
// Kernel 2/6: LayerNorm (one wave per 256-elem row), optional +ctx residual
// ---------------------------------------------------------------------------
template <int ADD_CTX>
__global__ __launch_bounds__(256) void ln_kernel(
    const float* __restrict__ x, const ushort_t* __restrict__ ctx,
    const float* __restrict__ g, const float* __restrict__ beta,
    ushort_t* __restrict__ out) {
    int wid = threadIdx.x >> 6, lane = threadIdx.x & 63;
    size_t row = (size_t)blockIdx.x * 4 + wid;
    size_t base = row * 256 + lane * 4;
    float4 v = *(const float4*)(x + base);
    if (ADD_CTX) {
        ushort4v c = *(const ushort4v*)(ctx + base);
        v.x += bf2f(c[0]); v.y += bf2f(c[1]);
        v.z += bf2f(c[2]); v.w += bf2f(c[3]);
    }
    float s  = v.x + v.y + v.z + v.w;
    float s2 = v.x * v.x + v.y * v.y + v.z * v.z + v.w * v.w;
#pragma unroll
    for (int msk = 1; msk < 64; msk <<= 1) {
        s  += __shfl_xor(s, msk);
        s2 += __shfl_xor(s2, msk);
    }
    float mu  = s * (1.f / 256.f);
    float var = s2 * (1.f / 256.f) - mu * mu;
    float rs  = rsqrtf(var + 1e-5f);
    const float4 gv = *(const float4*)(g + lane * 4);
    const float4 bv = *(const float4*)(beta + lane * 4);
    ushort4v o;
    o[0] = f2bf((v.x - mu) * rs * gv.x + bv.x);
    o[1] = f2bf((v.y - mu) * rs * gv.y + bv.y);
    o[2] = f2bf((v.z - mu) * rs * gv.z + bv.z);
    o[3] = f2bf((v.w - mu) * rs * gv.w + bv.w);
    *(ushort4v*)(out + base) = o;
}

// ---------------------------------------------------------------------------
// Kernels 3/7/8: GEMM C[M x N] = A[M x 256] @ B^T[N x 256]^T   (bf16, fp32 acc)
// ---------------------------------------------------------------------------
template <int EPI>
__global__ __launch_bounds__(256) void gemm_bt(
    const ushort_t* __restrict__ A, const ushort_t* __restrict__ B,
    void* __restrict__ Cp, const float* __restrict__ bias,
    const ushort_t* __restrict__ res, int nbn, int ldc) {
    __shared__ ushort_t lds_a[4096];  // [128][32]
    __shared__ ushort_t lds_b[4096];  // [128][32] (rows = output cols)
    int blk = blockIdx.x;
    int bn = blk % nbn, bm = blk / nbn;
    int m0 = bm * 128, n0 = bn * 128;
    int tid = threadIdx.x, wid = tid >> 6, lane = tid & 63;
    int fr = lane & 15, g = lane >> 4;
    int wm = (wid >> 1) * 64, wn = (wid & 1) * 64;

    f32x4 acc[4][4];
    const f32x4 fz = {0.f, 0.f, 0.f, 0.f};
#pragma unroll
    for (int m = 0; m < 4; m++)
#pragma unroll
        for (int n = 0; n < 4; n++) acc[m][n] = fz;

    for (int kt = 0; kt < 256; kt += 32) {
#pragma unroll
        for (int i = 0; i < 2; i++) {
            const ushort_t* as =
                A + (size_t)(m0 + i * 64 + (tid >> 2)) * 256 + kt + (tid & 3) * 8;
            gld_lds16(as, &lds_a[i * 2048 + wid * 512]);
            const ushort_t* bs =
                B + (size_t)(n0 + i * 64 + (tid >> 2)) * 256 + kt + (tid & 3) * 8;
            gld_lds16(bs, &lds_b[i * 2048 + wid * 512]);
        }
        __syncthreads();
        short8 af[4], bfr[4];
#pragma unroll
        for (int m = 0; m < 4; m++)
            af[m] = *(const short8*)&lds_a[(wm + m * 16 + fr) * 32 + g * 8];
#pragma unroll
        for (int n = 0; n < 4; n++)
            bfr[n] = *(const short8*)&lds_b[(wn + n * 16 + fr) * 32 + g * 8];
#pragma unroll
        for (int m = 0; m < 4; m++)
#pragma unroll
            for (int n = 0; n < 4; n++)
                acc[m][n] = __builtin_amdgcn_mfma_f32_16x16x32_bf16(
                    af[m], bfr[n], acc[m][n], 0, 0, 0);
        __syncthreads();
    }

#pragma unroll
    for (int m = 0; m < 4; m++)
#pragma unroll
        for (int n = 0; n < 4; n++) {
            int col = n0 + wn + n * 16 + fr;
            float bv = (EPI >= 1) ? bias[col] : 0.f;
#pragma unroll
            for (int j = 0; j < 4; j++) {
                size_t row = (size_t)(m0 + wm + m * 16 + g * 4 + j);
                float v = acc[m][n][j] + bv;
                if (EPI == 1) v = fmaxf(v, 0.f);
                if (EPI == 2) {
                    v += bf2f(res[row * 256 + col]);
                    ((float*)Cp)[row * ldc + col] = v;
                } else {
                    ((ushort_t*)Cp)[row * ldc + col] = f2bf(v);
                }
            }
        }
}

// ---------------------------------------------------------------------------
// Kernel 4: V transpose + PV-fragment permutation.
//   vt[bh][hd][slot] = V[b, key, h, hd]  with  key = pi(slot):
//   within each 32-key chunk, slot g*8+i  <-  key (i<4 ? g*4+i : 16+g*4+i-4).
// This makes the swapped-QK^T P registers directly usable as the PV
// A-fragment (no cross-lane exchange, no LDS round-trip).
// ---------------------------------------------------------------------------
__global__ __launch_bounds__(256) void vtrans(const ushort_t* __restrict__ qkv,
                                              ushort_t* __restrict__ vt) {
    __shared__ ushort_t tile[128][40];  // padded rows
    int bh = blockIdx.x >> 3, sb = blockIdx.x & 7;
    int b = bh >> 3, h = bh & 7;
    int t = threadIdx.x;
    int s0 = sb * 128;
#pragma unroll
    for (int i = 0; i < 2; i++) {
        int s = i * 64 + (t >> 2);
        int hd0 = (t & 3) * 8;
        short8 v = *(const short8*)(qkv + ((size_t)b * SEQ + s0 + s) * 768 + 512 +
                                    h * 32 + hd0);
        *(short8*)&tile[s][hd0] = v;
    }
    __syncthreads();
    int hd = t >> 3, c0 = (t & 7) * 16;
    short8 o0, o1;
#pragma unroll
    for (int i = 0; i < 8; i++) {
        int d = c0 + i, p = d & 31, gg = p >> 3, ii = p & 7;
        int src = (d & ~31) + (ii < 4 ? gg * 4 + ii : 16 + gg * 4 + ii - 4);
        o0[i] = (short)tile[src][hd];
    }
#pragma unroll
    for (int i = 0; i < 8; i++) {
        int d = c0 + 8 + i, p = d & 31, gg = p >> 3, ii = p & 7;
        int src = (d & ~31) + (ii < 4 ? gg * 4 + ii : 16 + gg * 4 + ii - 4);
        o1[i] = (short)tile[src][hd];
    }
    ushort_t* dst = vt + (size_t)bh * 32768 + (size_t)hd * 1024 + s0 + c0;
    *(short8*)dst = o0;
    *(short8*)(dst + 8) = o1;
}

// ---------------------------------------------------------------------------
// Kernel 5: flash attention, swapped-QK^T, zero LDS / zero barriers.
// Block = (b,h) x 128 Q-rows; 4 waves x 32 rows; KVBLK=128.
// s[n][m] = mfma(K-frag, Q-frag): lane (fr,g) holds score[q=m*16+fr][key=n*16+g*4+j]
//   -> row softmax = in-lane reduce + shfl_xor(16/32); running m,l are scalars.
// PV: V rows pre-permuted (vtrans) so P registers pack (cvt_pk) directly into
// the A-fragment. K/V fragments loaded straight from global (L1/L2-resident).
// ---------------------------------------------------------------------------
__global__ __launch_bounds__(256) void attn_kernel(
    const ushort_t* __restrict__ qkv, const ushort_t* __restrict__ vt,
    ushort_t* __restrict__ ctx) {
    int bh = blockIdx.x >> 3, qt = blockIdx.x & 7;
    int b = bh >> 3, h = bh & 7;
    int tid = threadIdx.x, wid = tid >> 6, lane = tid & 63;
    int fr = lane & 15, g = lane >> 4;
    int q0 = qt * 128 + wid * 32;
    const ushort_t* qbase = qkv + (size_t)b * SEQ * 768;
    const ushort_t* vbase = vt + (size_t)bh * 32768;

    // Q fragments (B operand of swapped QK^T); Q is pre-scaled by log2(e)
    short8 qb[2];
#pragma unroll
    for (int m = 0; m < 2; m++)
        qb[m] = *(const short8*)(qbase + (size_t)(q0 + m * 16 + fr) * 768 +
                                 h * 32 + g * 8);

    f32x4 acc[2][2];
    const f32x4 fz = {0.f, 0.f, 0.f, 0.f};
#pragma unroll
    for (int m = 0; m < 2; m++)
#pragma unroll
        for (int n = 0; n < 2; n++) acc[m][n] = fz;
    float mrun[2] = {-1e30f, -1e30f};
    float lrun[2] = {0.f, 0.f};

    for (int kv = 0; kv < SEQ; kv += 128) {
        // ---- scores (log2 domain): s[n][m][j] = S[key=n*16+g*4+j][q=m*16+fr]
        f32x4 s[8][2];
#pragma unroll
        for (int n = 0; n < 8; n++) {
            short8 kb = *(const short8*)(qbase +
                                         (size_t)(kv + n * 16 + fr) * 768 + 256 +
                                         h * 32 + g * 8);
#pragma unroll
            for (int m = 0; m < 2; m++)
                s[n][m] = __builtin_amdgcn_mfma_f32_16x16x32_bf16(kb, qb[m], fz,
                                                                  0, 0, 0);
        }

        // ---- online softmax, one q-row per lane (per m)
#pragma unroll
        for (int m = 0; m < 2; m++) {
            float mx = s[0][m][0];
#pragma unroll
            for (int n = 0; n < 8; n++)
#pragma unroll
                for (int j = 0; j < 4; j++)
                    if (n || j) mx = fmaxf(mx, s[n][m][j]);
            mx = fmaxf(mx, __shfl_xor(mx, 16));
            mx = fmaxf(mx, __shfl_xor(mx, 32));
            if (__all(mx - mrun[m] <= 11.5f)) {
                // deferred max: keep old max, P bounded by 2^11.5
                float sum = 0.f;
#pragma unroll
                for (int n = 0; n < 8; n++)
#pragma unroll
                    for (int j = 0; j < 4; j++) {
                        float p = exp2_fast(s[n][m][j] - mrun[m]);
                        s[n][m][j] = p;
                        sum += p;
                    }
                sum += __shfl_xor(sum, 16);
                sum += __shfl_xor(sum, 32);
                lrun[m] += sum;
            } else {
                float mnew = fmaxf(mrun[m], mx);
                float scl = exp2_fast(mrun[m] - mnew);
                // rescale acc: acc rows are q=g*4+j -> fetch that row's scl
#pragma unroll
                for (int j = 0; j < 4; j++) {
                    float sj = __shfl(scl, g * 4 + j);
                    acc[m][0][j] *= sj;
                    acc[m][1][j] *= sj;
                }
                float sum = 0.f;
#pragma unroll
                for (int n = 0; n < 8; n++)
#pragma unroll
                    for (int j = 0; j < 4; j++) {
                        float p = exp2_fast(s[n][m][j] - mnew);
                        s[n][m][j] = p;
                        sum += p;
                    }
                sum += __shfl_xor(sum, 16);
                sum += __shfl_xor(sum, 32);
                lrun[m] = lrun[m] * scl + sum;
                mrun[m] = mnew;
            }
        }

        // ---- PV: P packs in-lane into the A-fragment (V rows pre-permuted)
#pragma unroll
        for (int kk = 0; kk < 4; kk++) {
            short8 vb[2];
#pragma unroll
            for (int n = 0; n < 2; n++)
                vb[n] = *(const short8*)(vbase + (size_t)(n * 16 + fr) * 1024 +
                                         kv + kk * 32 + g * 8);
#pragma unroll
            for (int m = 0; m < 2; m++) {
                union { short8 s8; uint32_t u[4]; } pa;
                asm("v_cvt_pk_bf16_f32 %0, %1, %2"
                    : "=v"(pa.u[0])
                    : "v"(s[2 * kk][m][0]), "v"(s[2 * kk][m][1]));
                asm("v_cvt_pk_bf16_f32 %0, %1, %2"
                    : "=v"(pa.u[1])
                    : "v"(s[2 * kk][m][2]), "v"(s[2 * kk][m][3]));
                asm("v_cvt_pk_bf16_f32 %0, %1, %2"
                    : "=v"(pa.u[2])
                    : "v"(s[2 * kk + 1][m][0]), "v"(s[2 * kk + 1][m][1]));
                asm("v_cvt_pk_bf16_f32 %0, %1, %2"
                    : "=v"(pa.u[3])
                    : "v"(s[2 * kk + 1][m][2]), "v"(s[2 * kk + 1][m][3]));
#pragma unroll
                for (int n = 0; n < 2; n++)
                    acc[m][n] = __builtin_amdgcn_mfma_f32_16x16x32_bf16(
                        pa.s8, vb[n], acc[m][n], 0, 0, 0);
            }
        }
    }

    // ---- epilogue: lane (fr,g) holds ctx[q=m*16+g*4+j][hd=n*16+fr]
#pragma unroll
    for (int m = 0; m < 2; m++)
#pragma unroll
        for (int j = 0; j < 4; j++) {
            float lr = __shfl(lrun[m], g * 4 + j);
            float inv = 1.f / lr;
#pragma unroll
            for (int n = 0; n < 2; n++) {
                size_t row = (size_t)b * SEQ + q0 + m * 16 + g * 4 + j;
                ctx[row * 256 + h * 32 + n * 16 + fr] =
                    f2bf(acc[m][n][j] * inv);
            }
        }
}

// ---------------------------------------------------------------------------
extern "C" void kernel_launch(void* const* d_in, const int* in_sizes, int n_in,
                              void* d_out, int out_size, void* d_ws,
                              size_t ws_size, hipStream_t stream) {
    const float* x   = (const float*)d_in[0];
    const float* wq  = (const float*)d_in[1];
    const float* wk  = (const float*)d_in[2];
    const float* wv  = (const float*)d_in[3];
    const float* g1  = (const float*)d_in[4];
    const float* be1 = (const float*)d_in[5];
    const float* g2  = (const float*)d_in[6];
    const float* be2 = (const float*)d_in[7];
    const float* wf1 = (const float*)d_in[8];
    const float* bf1 = (const float*)d_in[9];
    const float* wf2 = (const float*)d_in[10];
    const float* bf2 = (const float*)d_in[11];

    char* ws = (char*)d_ws;
    const size_t SZ16M = (size_t)ROWS * 256 * 2;  // 16 MiB
    ushort_t* wqkvT = (ushort_t*)(ws);                      // 768*256*2
    ushort_t* wf1T  = (ushort_t*)(ws + 393216);
    ushort_t* wf2T  = (ushort_t*)(ws + 524288);
    ushort_t* xn    = (ushort_t*)(ws + 655360);             // 16 MiB (reused as h)
    ushort_t* qkvb  = (ushort_t*)(ws + 655360 + SZ16M);     // 48 MiB
    ushort_t* vtb   = (ushort_t*)(ws + 655360 + SZ16M + (size_t)ROWS * 768 * 2);
    ushort_t* ctxb  = (ushort_t*)((char*)vtb + SZ16M);
    ushort_t* ab    = (ushort_t*)((char*)ctxb + SZ16M);
    ushort_t* hb    = xn;  // xn dead after QKV GEMM

    prep_weights<<<dim3(1280), dim3(256), 0, stream>>>(wq, wk, wv, wf1, wf2,
                                                       wqkvT, wf1T, wf2T);
    ln_kernel<0><<<dim3(ROWS / 4), dim3(256), 0, stream>>>(x, nullptr, g1, be1,
                                                           xn);
    gemm_bt<0><<<dim3(256 * 6), dim3(256), 0, stream>>>(xn, wqkvT, (void*)qkvb,
                                                        nullptr, nullptr, 6, 768);
    vtrans<<<dim3(2048), dim3(256), 0, stream>>>(qkvb, vtb);
    attn_kernel<<<dim3(2048), dim3(256), 0, stream>>>(qkvb, vtb, ctxb);
    ln_kernel<1><<<dim3(ROWS / 4), dim3(256), 0, stream>>>(x, ctxb, g2, be2, ab);
    gemm_bt<1><<<dim3(256 * 2), dim3(256), 0, stream>>>(ab, wf1T, (void*)hb, bf1,
                                                        nullptr, 2, 256);
    gemm_bt<2><<<dim3(256 * 2), dim3(256), 0, stream>>>(hb, wf2T, d_out, bf2, ab,
                                                        2, 256);
}

// Round 3
// 210.745 us; speedup vs baseline: 1.1411x; 1.1175x over previous
//
#include <hip/hip_runtime.h>
#include <stdint.h>

typedef unsigned short ushort_t;
typedef __attribute__((ext_vector_type(8))) short short8;
typedef __attribute__((ext_vector_type(4))) float f32x4;
typedef __attribute__((ext_vector_type(4))) unsigned short ushort4v;

#define NBATCH 32
#define SEQ 1024
#define DIM 256
#define NH 8
#define ROWS (NBATCH * SEQ)   // 32768

__device__ __forceinline__ ushort_t f2bf(float f) {
    uint32_t u = __float_as_uint(f);
    u += 0x7fffu + ((u >> 16) & 1u);   // round-to-nearest-even
    return (ushort_t)(u >> 16);
}
__device__ __forceinline__ float bf2f(ushort_t h) {
    return __uint_as_float(((uint32_t)h) << 16);
}
__device__ __forceinline__ float exp2_fast(float x) {
    float r;
    asm("v_exp_f32 %0, %1" : "=v"(r) : "v"(x));
    return r;
}

typedef __attribute__((address_space(3))) void lds_void_t;
typedef const __attribute__((address_space(1))) void glob_void_t;
__device__ __forceinline__ void gld_lds16(const void* g, void* l) {
    __builtin_amdgcn_global_load_lds((glob_void_t*)g, (lds_void_t*)l, 16, 0, 0);
}

// ---------------------------------------------------------------------------
// Kernel 1: weight prep — wT[n][k] = (bf16) w[k][n] for wq|wk|wv packed, wf1, wf2
// wq additionally scaled by log2(e): attention softmax runs in exp2 domain.
// ---------------------------------------------------------------------------
__global__ __launch_bounds__(256) void prep_weights(
    const float* __restrict__ wq, const float* __restrict__ wk,
    const float* __restrict__ wv, const float* __restrict__ wf1,
    const float* __restrict__ wf2, ushort_t* __restrict__ wqkvT,
    ushort_t* __restrict__ wf1T, ushort_t* __restrict__ wf2T) {
    int n = blockIdx.x;
    int k = threadIdx.x;
    if (n < 768) {
        const float* w = (n < 256) ? wq : (n < 512 ? wk : wv);
        int nn = n & 255;
        float v = w[k * 256 + nn];
        if (n < 256) v *= 1.4426950408889634f;  // log2(e) fold for exp2 softmax
        wqkvT[n * 256 + k] = f2bf(v);
    } else if (n < 1024) {
        int nn = n - 768;
        wf1T[nn * 256 + k] = f2bf(wf1[k * 256 + nn]);
    } else {
        int nn = n - 1024;
        wf2T[nn * 256 + k] = f2bf(wf2[k * 256 + nn]);
    }
}

// ---------------------------------------------------------------------------
// Kernel 2/6: LayerNorm (one wave per 256-elem row), optional +ctx residual
// ---------------------------------------------------------------------------
template <int ADD_CTX>
__global__ __launch_bounds__(256) void ln_kernel(
    const float* __restrict__ x, const ushort_t* __restrict__ ctx,
    const float* __restrict__ g, const float* __restrict__ beta,
    ushort_t* __restrict__ out) {
    int wid = threadIdx.x >> 6, lane = threadIdx.x & 63;
    size_t row = (size_t)blockIdx.x * 4 + wid;
    size_t base = row * 256 + lane * 4;
    float4 v = *(const float4*)(x + base);
    if (ADD_CTX) {
        ushort4v c = *(const ushort4v*)(ctx + base);
        v.x += bf2f(c[0]); v.y += bf2f(c[1]);
        v.z += bf2f(c[2]); v.w += bf2f(c[3]);
    }
    float s  = v.x + v.y + v.z + v.w;
    float s2 = v.x * v.x + v.y * v.y + v.z * v.z + v.w * v.w;
#pragma unroll
    for (int msk = 1; msk < 64; msk <<= 1) {
        s  += __shfl_xor(s, msk);
        s2 += __shfl_xor(s2, msk);
    }
    float mu  = s * (1.f / 256.f);
    float var = s2 * (1.f / 256.f) - mu * mu;
    float rs  = rsqrtf(var + 1e-5f);
    const float4 gv = *(const float4*)(g + lane * 4);
    const float4 bv = *(const float4*)(beta + lane * 4);
    ushort4v o;
    o[0] = f2bf((v.x - mu) * rs * gv.x + bv.x);
    o[1] = f2bf((v.y - mu) * rs * gv.y + bv.y);
    o[2] = f2bf((v.z - mu) * rs * gv.z + bv.z);
    o[3] = f2bf((v.w - mu) * rs * gv.w + bv.w);
    *(ushort4v*)(out + base) = o;
}

// ---------------------------------------------------------------------------
// Kernels 3/7/8: GEMM C[M x N] = A[M x 256] @ B^T[N x 256]^T   (bf16, fp32 acc)
// XCD-aware block swizzle (grid % 8 == 0 for all call sites).
// ---------------------------------------------------------------------------
template <int EPI>
__global__ __launch_bounds__(256) void gemm_bt(
    const ushort_t* __restrict__ A, const ushort_t* __restrict__ B,
    void* __restrict__ Cp, const float* __restrict__ bias,
    const ushort_t* __restrict__ res, int nbn, int ldc) {
    __shared__ ushort_t lds_a[4096];  // [128][32]
    __shared__ ushort_t lds_b[4096];  // [128][32] (rows = output cols)
    int cpx = gridDim.x >> 3;
    int blk = (blockIdx.x & 7) * cpx + (blockIdx.x >> 3);
    int bn = blk % nbn, bm = blk / nbn;
    int m0 = bm * 128, n0 = bn * 128;
    int tid = threadIdx.x, wid = tid >> 6, lane = tid & 63;
    int fr = lane & 15, g = lane >> 4;
    int wm = (wid >> 1) * 64, wn = (wid & 1) * 64;

    f32x4 acc[4][4];
    const f32x4 fz = {0.f, 0.f, 0.f, 0.f};
#pragma unroll
    for (int m = 0; m < 4; m++)
#pragma unroll
        for (int n = 0; n < 4; n++) acc[m][n] = fz;

    for (int kt = 0; kt < 256; kt += 32) {
#pragma unroll
        for (int i = 0; i < 2; i++) {
            const ushort_t* as =
                A + (size_t)(m0 + i * 64 + (tid >> 2)) * 256 + kt + (tid & 3) * 8;
            gld_lds16(as, &lds_a[i * 2048 + wid * 512]);
            const ushort_t* bs =
                B + (size_t)(n0 + i * 64 + (tid >> 2)) * 256 + kt + (tid & 3) * 8;
            gld_lds16(bs, &lds_b[i * 2048 + wid * 512]);
        }
        __syncthreads();
        short8 af[4], bfr[4];
#pragma unroll
        for (int m = 0; m < 4; m++)
            af[m] = *(const short8*)&lds_a[(wm + m * 16 + fr) * 32 + g * 8];
#pragma unroll
        for (int n = 0; n < 4; n++)
            bfr[n] = *(const short8*)&lds_b[(wn + n * 16 + fr) * 32 + g * 8];
#pragma unroll
        for (int m = 0; m < 4; m++)
#pragma unroll
            for (int n = 0; n < 4; n++)
                acc[m][n] = __builtin_amdgcn_mfma_f32_16x16x32_bf16(
                    af[m], bfr[n], acc[m][n], 0, 0, 0);
        __syncthreads();
    }

#pragma unroll
    for (int m = 0; m < 4; m++)
#pragma unroll
        for (int n = 0; n < 4; n++) {
            int col = n0 + wn + n * 16 + fr;
            float bv = (EPI >= 1) ? bias[col] : 0.f;
#pragma unroll
            for (int j = 0; j < 4; j++) {
                size_t row = (size_t)(m0 + wm + m * 16 + g * 4 + j);
                float v = acc[m][n][j] + bv;
                if (EPI == 1) v = fmaxf(v, 0.f);
                if (EPI == 2) {
                    v += bf2f(res[row * 256 + col]);
                    ((float*)Cp)[row * ldc + col] = v;
                } else {
                    ((ushort_t*)Cp)[row * ldc + col] = f2bf(v);
                }
            }
        }
}

// ---------------------------------------------------------------------------
// Kernel 4: V transpose + PV-fragment permutation.
//   vt[bh][hd][slot] = V[b, key, h, hd]  with  key = pi(slot):
//   within each 32-key chunk, slot g*8+i  <-  key (i<4 ? g*4+i : 16+g*4+i-4).
// ---------------------------------------------------------------------------
__global__ __launch_bounds__(256) void vtrans(const ushort_t* __restrict__ qkv,
                                              ushort_t* __restrict__ vt) {
    __shared__ ushort_t tile[128][40];  // padded rows
    int bh = blockIdx.x >> 3, sb = blockIdx.x & 7;
    int b = bh >> 3, h = bh & 7;
    int t = threadIdx.x;
    int s0 = sb * 128;
#pragma unroll
    for (int i = 0; i < 2; i++) {
        int s = i * 64 + (t >> 2);
        int hd0 = (t & 3) * 8;
        short8 v = *(const short8*)(qkv + ((size_t)b * SEQ + s0 + s) * 768 + 512 +
                                    h * 32 + hd0);
        *(short8*)&tile[s][hd0] = v;
    }
    __syncthreads();
    int hd = t >> 3, c0 = (t & 7) * 16;
    short8 o0, o1;
#pragma unroll
    for (int i = 0; i < 8; i++) {
        int d = c0 + i, p = d & 31, gg = p >> 3, ii = p & 7;
        int src = (d & ~31) + (ii < 4 ? gg * 4 + ii : 16 + gg * 4 + ii - 4);
        o0[i] = (short)tile[src][hd];
    }
#pragma unroll
    for (int i = 0; i < 8; i++) {
        int d = c0 + 8 + i, p = d & 31, gg = p >> 3, ii = p & 7;
        int src = (d & ~31) + (ii < 4 ? gg * 4 + ii : 16 + gg * 4 + ii - 4);
        o1[i] = (short)tile[src][hd];
    }
    ushort_t* dst = vt + (size_t)bh * 32768 + (size_t)hd * 1024 + s0 + c0;
    *(short8*)dst = o0;
    *(short8*)(dst + 8) = o1;
}

// ---------------------------------------------------------------------------
// Kernel 5: flash attention, swapped-QK^T, zero LDS, software-pipelined.
// Per iter: issue V loads -> QK^T (regs) -> prefetch next K -> tree softmax -> PV.
// V latency hides under softmax; K latency hides under softmax+PV.
// XCD swizzle groups the 8 q-tile blocks of one (b,h) onto one XCD (K/V L2 reuse).
// ---------------------------------------------------------------------------
__global__ __launch_bounds__(256) void attn_kernel(
    const ushort_t* __restrict__ qkv, const ushort_t* __restrict__ vt,
    ushort_t* __restrict__ ctx) {
    int cpx = gridDim.x >> 3;
    int wgid = (blockIdx.x & 7) * cpx + (blockIdx.x >> 3);
    int bh = wgid >> 3, qt = wgid & 7;
    int b = bh >> 3, h = bh & 7;
    int tid = threadIdx.x, wid = tid >> 6, lane = tid & 63;
    int fr = lane & 15, g = lane >> 4;
    int q0 = qt * 128 + wid * 32;
    const ushort_t* qbase = qkv + (size_t)b * SEQ * 768;
    const ushort_t* vbase = vt + (size_t)bh * 32768;

    // Q fragments (B operand of swapped QK^T); Q pre-scaled by log2(e)
    short8 qb[2];
#pragma unroll
    for (int m = 0; m < 2; m++)
        qb[m] = *(const short8*)(qbase + (size_t)(q0 + m * 16 + fr) * 768 +
                                 h * 32 + g * 8);

    f32x4 acc[2][2];
    const f32x4 fz = {0.f, 0.f, 0.f, 0.f};
#pragma unroll
    for (int m = 0; m < 2; m++)
#pragma unroll
        for (int n = 0; n < 2; n++) acc[m][n] = fz;
    float mrun[2] = {-1e30f, -1e30f};
    float lrun[2] = {0.f, 0.f};

    // per-lane K base (row = kv + n*16 + fr), V bases (rows fr and 16+fr)
    const ushort_t* kb_base = qbase + 256 + h * 32 + g * 8 + (size_t)fr * 768;
    const ushort_t* vp0 = vbase + (size_t)fr * 1024 + g * 8;
    const ushort_t* vp1 = vbase + (size_t)(16 + fr) * 1024 + g * 8;

    // prefetch first K tile
    short8 kreg[8];
#pragma unroll
    for (int n = 0; n < 8; n++)
        kreg[n] = *(const short8*)(kb_base + (size_t)(n * 16) * 768);

    for (int kv = 0; kv < SEQ; kv += 128) {
        // ---- issue V loads for this tile (in flight through QK^T + softmax)
        short8 vreg[4][2];
#pragma unroll
        for (int kk = 0; kk < 4; kk++) {
            vreg[kk][0] = *(const short8*)(vp0 + kv + kk * 32);
            vreg[kk][1] = *(const short8*)(vp1 + kv + kk * 32);
        }

        // ---- scores (log2 domain): s[n][m][j] = S[key=n*16+g*4+j][q=m*16+fr]
        f32x4 s[8][2];
#pragma unroll
        for (int n = 0; n < 8; n++)
#pragma unroll
            for (int m = 0; m < 2; m++)
                s[n][m] = __builtin_amdgcn_mfma_f32_16x16x32_bf16(kreg[n], qb[m],
                                                                  fz, 0, 0, 0);

        // ---- prefetch next K tile (completes during softmax + PV)
        if (kv + 128 < SEQ) {
#pragma unroll
            for (int n = 0; n < 8; n++)
                kreg[n] = *(const short8*)(kb_base +
                                           (size_t)(kv + 128 + n * 16) * 768);
        }

        // ---- row max, pairwise trees (one q-row per lane, per m)
        float mx[2];
#pragma unroll
        for (int m = 0; m < 2; m++) {
            float t[8];
#pragma unroll
            for (int n = 0; n < 8; n++)
                t[n] = fmaxf(fmaxf(s[n][m][0], s[n][m][1]),
                             fmaxf(s[n][m][2], s[n][m][3]));
            float a = fmaxf(fmaxf(t[0], t[1]), fmaxf(t[2], t[3]));
            float c = fmaxf(fmaxf(t[4], t[5]), fmaxf(t[6], t[7]));
            mx[m] = fmaxf(a, c);
        }
#pragma unroll
        for (int m = 0; m < 2; m++) {
            mx[m] = fmaxf(mx[m], __shfl_xor(mx[m], 16));
            mx[m] = fmaxf(mx[m], __shfl_xor(mx[m], 32));
        }

        // ---- deferred-max: rescale only when a row max grew by >11.5 (log2)
        bool ok = (mx[0] - mrun[0] <= 11.5f) && (mx[1] - mrun[1] <= 11.5f);
        if (!__all(ok)) {
#pragma unroll
            for (int m = 0; m < 2; m++) {
                float mnew = fmaxf(mrun[m], mx[m]);
                float scl = exp2_fast(mrun[m] - mnew);
#pragma unroll
                for (int j = 0; j < 4; j++) {
                    float sj = __shfl(scl, g * 4 + j);
                    acc[m][0][j] *= sj;
                    acc[m][1][j] *= sj;
                }
                lrun[m] *= scl;   // lrun rows match lane rows (q = fr)
                mrun[m] = mnew;
            }
        }

        // ---- exp + row-sum trees
#pragma unroll
        for (int m = 0; m < 2; m++) {
            float r[8];
#pragma unroll
            for (int n = 0; n < 8; n++) {
                float p0 = exp2_fast(s[n][m][0] - mrun[m]);
                float p1 = exp2_fast(s[n][m][1] - mrun[m]);
                float p2 = exp2_fast(s[n][m][2] - mrun[m]);
                float p3 = exp2_fast(s[n][m][3] - mrun[m]);
                s[n][m][0] = p0; s[n][m][1] = p1;
                s[n][m][2] = p2; s[n][m][3] = p3;
                r[n] = (p0 + p1) + (p2 + p3);
            }
            float a = (r[0] + r[1]) + (r[2] + r[3]);
            float c = (r[4] + r[5]) + (r[6] + r[7]);
            float sum = a + c;
            sum += __shfl_xor(sum, 16);
            sum += __shfl_xor(sum, 32);
            lrun[m] += sum;
        }

        // ---- PV: P packs in-lane into A-fragment (V rows pre-permuted)
#pragma unroll
        for (int kk = 0; kk < 4; kk++) {
#pragma unroll
            for (int m = 0; m < 2; m++) {
                union { short8 s8; uint32_t u[4]; } pa;
                asm("v_cvt_pk_bf16_f32 %0, %1, %2"
                    : "=v"(pa.u[0])
                    : "v"(s[2 * kk][m][0]), "v"(s[2 * kk][m][1]));
                asm("v_cvt_pk_bf16_f32 %0, %1, %2"
                    : "=v"(pa.u[1])
                    : "v"(s[2 * kk][m][2]), "v"(s[2 * kk][m][3]));
                asm("v_cvt_pk_bf16_f32 %0, %1, %2"
                    : "=v"(pa.u[2])
                    : "v"(s[2 * kk + 1][m][0]), "v"(s[2 * kk + 1][m][1]));
                asm("v_cvt_pk_bf16_f32 %0, %1, %2"
                    : "=v"(pa.u[3])
                    : "v"(s[2 * kk + 1][m][2]), "v"(s[2 * kk + 1][m][3]));
#pragma unroll
                for (int n = 0; n < 2; n++)
                    acc[m][n] = __builtin_amdgcn_mfma_f32_16x16x32_bf16(
                        pa.s8, vreg[kk][n], acc[m][n], 0, 0, 0);
            }
        }
    }

    // ---- epilogue: lane (fr,g) holds ctx[q=m*16+g*4+j][hd=n*16+fr]
#pragma unroll
    for (int m = 0; m < 2; m++)
#pragma unroll
        for (int j = 0; j < 4; j++) {
            float lr = __shfl(lrun[m], g * 4 + j);
            float inv = 1.f / lr;
#pragma unroll
            for (int n = 0; n < 2; n++) {
                size_t row = (size_t)b * SEQ + q0 + m * 16 + g * 4 + j;
                ctx[row * 256 + h * 32 + n * 16 + fr] =
                    f2bf(acc[m][n][j] * inv);
            }
        }
}

// ---------------------------------------------------------------------------
extern "C" void kernel_launch(void* const* d_in, const int* in_sizes, int n_in,
                              void* d_out, int out_size, void* d_ws,
                              size_t ws_size, hipStream_t stream) {
    const float* x   = (const float*)d_in[0];
    const float* wq  = (const float*)d_in[1];
    const float* wk  = (const float*)d_in[2];
    const float* wv  = (const float*)d_in[3];
    const float* g1  = (const float*)d_in[4];
    const float* be1 = (const float*)d_in[5];
    const float* g2  = (const float*)d_in[6];
    const float* be2 = (const float*)d_in[7];
    const float* wf1 = (const float*)d_in[8];
    const float* bf1 = (const float*)d_in[9];
    const float* wf2 = (const float*)d_in[10];
    const float* bf2 = (const float*)d_in[11];

    char* ws = (char*)d_ws;
    const size_t SZ16M = (size_t)ROWS * 256 * 2;  // 16 MiB
    ushort_t* wqkvT = (ushort_t*)(ws);                      // 768*256*2
    ushort_t* wf1T  = (ushort_t*)(ws + 393216);
    ushort_t* wf2T  = (ushort_t*)(ws + 524288);
    ushort_t* xn    = (ushort_t*)(ws + 655360);             // 16 MiB (reused as h)
    ushort_t* qkvb  = (ushort_t*)(ws + 655360 + SZ16M);     // 48 MiB
    ushort_t* vtb   = (ushort_t*)(ws + 655360 + SZ16M + (size_t)ROWS * 768 * 2);
    ushort_t* ctxb  = (ushort_t*)((char*)vtb + SZ16M);
    ushort_t* ab    = (ushort_t*)((char*)ctxb + SZ16M);
    ushort_t* hb    = xn;  // xn dead after QKV GEMM

    prep_weights<<<dim3(1280), dim3(256), 0, stream>>>(wq, wk, wv, wf1, wf2,
                                                       wqkvT, wf1T, wf2T);
    ln_kernel<0><<<dim3(ROWS / 4), dim3(256), 0, stream>>>(x, nullptr, g1, be1,
                                                           xn);
    gemm_bt<0><<<dim3(256 * 6), dim3(256), 0, stream>>>(xn, wqkvT, (void*)qkvb,
                                                        nullptr, nullptr, 6, 768);
    vtrans<<<dim3(2048), dim3(256), 0, stream>>>(qkvb, vtb);
    attn_kernel<<<dim3(2048), dim3(256), 0, stream>>>(qkvb, vtb, ctxb);
    ln_kernel<1><<<dim3(ROWS / 4), dim3(256), 0, stream>>>(x, ctxb, g2, be2, ab);
    gemm_bt<1><<<dim3(256 * 2), dim3(256), 0, stream>>>(ab, wf1T, (void*)hb, bf1,
                                                        nullptr, 2, 256);
    gemm_bt<2><<<dim3(256 * 2), dim3(256), 0, stream>>>(hb, wf2T, d_out, bf2, ab,
                                                        2, 256);
}

// Round 4
// 200.713 us; speedup vs baseline: 1.1981x; 1.0500x over previous
//
#include <hip/hip_runtime.h>
#include <stdint.h>

typedef unsigned short ushort_t;
typedef __attribute__((ext_vector_type(8))) short short8;
typedef __attribute__((ext_vector_type(4))) float f32x4;
typedef __attribute__((ext_vector_type(4))) unsigned short ushort4v;

#define NBATCH 32
#define SEQ 1024
#define DIM 256
#define NH 8
#define ROWS (NBATCH * SEQ)   // 32768

__device__ __forceinline__ ushort_t f2bf(float f) {
    uint32_t u = __float_as_uint(f);
    u += 0x7fffu + ((u >> 16) & 1u);   // round-to-nearest-even
    return (ushort_t)(u >> 16);
}
__device__ __forceinline__ float bf2f(ushort_t h) {
    return __uint_as_float(((uint32_t)h) << 16);
}
__device__ __forceinline__ float exp2_fast(float x) {
    float r;
    asm("v_exp_f32 %0, %1" : "=v"(r) : "v"(x));
    return r;
}

typedef __attribute__((address_space(3))) void lds_void_t;
typedef const __attribute__((address_space(1))) void glob_void_t;
__device__ __forceinline__ void gld_lds16(const void* g, void* l) {
    __builtin_amdgcn_global_load_lds((glob_void_t*)g, (lds_void_t*)l, 16, 0, 0);
}

// ---------------------------------------------------------------------------
// Kernel 1: weight prep — wT[n][k] = (bf16) w[k][n] for wq|wk|wv packed, wf1, wf2
// wq additionally scaled by log2(e): attention softmax runs in exp2 domain.
// ---------------------------------------------------------------------------
__global__ __launch_bounds__(256) void prep_weights(
    const float* __restrict__ wq, const float* __restrict__ wk,
    const float* __restrict__ wv, const float* __restrict__ wf1,
    const float* __restrict__ wf2, ushort_t* __restrict__ wqkvT,
    ushort_t* __restrict__ wf1T, ushort_t* __restrict__ wf2T) {
    int n = blockIdx.x;
    int k = threadIdx.x;
    if (n < 768) {
        const float* w = (n < 256) ? wq : (n < 512 ? wk : wv);
        int nn = n & 255;
        float v = w[k * 256 + nn];
        if (n < 256) v *= 1.4426950408889634f;  // log2(e) fold for exp2 softmax
        wqkvT[n * 256 + k] = f2bf(v);
    } else if (n < 1024) {
        int nn = n - 768;
        wf1T[nn * 256 + k] = f2bf(wf1[k * 256 + nn]);
    } else {
        int nn = n - 1024;
        wf2T[nn * 256 + k] = f2bf(wf2[k * 256 + nn]);
    }
}

// ---------------------------------------------------------------------------
// Kernel 2/6: LayerNorm (one wave per 256-elem row), optional +ctx residual
// ---------------------------------------------------------------------------
template <int ADD_CTX>
__global__ __launch_bounds__(256) void ln_kernel(
    const float* __restrict__ x, const ushort_t* __restrict__ ctx,
    const float* __restrict__ g, const float* __restrict__ beta,
    ushort_t* __restrict__ out) {
    int wid = threadIdx.x >> 6, lane = threadIdx.x & 63;
    size_t row = (size_t)blockIdx.x * 4 + wid;
    size_t base = row * 256 + lane * 4;
    float4 v = *(const float4*)(x + base);
    if (ADD_CTX) {
        ushort4v c = *(const ushort4v*)(ctx + base);
        v.x += bf2f(c[0]); v.y += bf2f(c[1]);
        v.z += bf2f(c[2]); v.w += bf2f(c[3]);
    }
    float s  = v.x + v.y + v.z + v.w;
    float s2 = v.x * v.x + v.y * v.y + v.z * v.z + v.w * v.w;
#pragma unroll
    for (int msk = 1; msk < 64; msk <<= 1) {
        s  += __shfl_xor(s, msk);
        s2 += __shfl_xor(s2, msk);
    }
    float mu  = s * (1.f / 256.f);
    float var = s2 * (1.f / 256.f) - mu * mu;
    float rs  = rsqrtf(var + 1e-5f);
    const float4 gv = *(const float4*)(g + lane * 4);
    const float4 bv = *(const float4*)(beta + lane * 4);
    ushort4v o;
    o[0] = f2bf((v.x - mu) * rs * gv.x + bv.x);
    o[1] = f2bf((v.y - mu) * rs * gv.y + bv.y);
    o[2] = f2bf((v.z - mu) * rs * gv.z + bv.z);
    o[3] = f2bf((v.w - mu) * rs * gv.w + bv.w);
    *(ushort4v*)(out + base) = o;
}

// ---------------------------------------------------------------------------
// Kernels 3/7/8: GEMM C[M x N] = A[M x 256] @ B^T[N x 256]^T   (bf16, fp32 acc)
// XCD-aware block swizzle (grid % 8 == 0 for all call sites).
// ---------------------------------------------------------------------------
template <int EPI>
__global__ __launch_bounds__(256) void gemm_bt(
    const ushort_t* __restrict__ A, const ushort_t* __restrict__ B,
    void* __restrict__ Cp, const float* __restrict__ bias,
    const ushort_t* __restrict__ res, int nbn, int ldc) {
    __shared__ ushort_t lds_a[4096];  // [128][32]
    __shared__ ushort_t lds_b[4096];  // [128][32] (rows = output cols)
    int cpx = gridDim.x >> 3;
    int blk = (blockIdx.x & 7) * cpx + (blockIdx.x >> 3);
    int bn = blk % nbn, bm = blk / nbn;
    int m0 = bm * 128, n0 = bn * 128;
    int tid = threadIdx.x, wid = tid >> 6, lane = tid & 63;
    int fr = lane & 15, g = lane >> 4;
    int wm = (wid >> 1) * 64, wn = (wid & 1) * 64;

    f32x4 acc[4][4];
    const f32x4 fz = {0.f, 0.f, 0.f, 0.f};
#pragma unroll
    for (int m = 0; m < 4; m++)
#pragma unroll
        for (int n = 0; n < 4; n++) acc[m][n] = fz;

    for (int kt = 0; kt < 256; kt += 32) {
#pragma unroll
        for (int i = 0; i < 2; i++) {
            const ushort_t* as =
                A + (size_t)(m0 + i * 64 + (tid >> 2)) * 256 + kt + (tid & 3) * 8;
            gld_lds16(as, &lds_a[i * 2048 + wid * 512]);
            const ushort_t* bs =
                B + (size_t)(n0 + i * 64 + (tid >> 2)) * 256 + kt + (tid & 3) * 8;
            gld_lds16(bs, &lds_b[i * 2048 + wid * 512]);
        }
        __syncthreads();
        short8 af[4], bfr[4];
#pragma unroll
        for (int m = 0; m < 4; m++)
            af[m] = *(const short8*)&lds_a[(wm + m * 16 + fr) * 32 + g * 8];
#pragma unroll
        for (int n = 0; n < 4; n++)
            bfr[n] = *(const short8*)&lds_b[(wn + n * 16 + fr) * 32 + g * 8];
#pragma unroll
        for (int m = 0; m < 4; m++)
#pragma unroll
            for (int n = 0; n < 4; n++)
                acc[m][n] = __builtin_amdgcn_mfma_f32_16x16x32_bf16(
                    af[m], bfr[n], acc[m][n], 0, 0, 0);
        __syncthreads();
    }

#pragma unroll
    for (int m = 0; m < 4; m++)
#pragma unroll
        for (int n = 0; n < 4; n++) {
            int col = n0 + wn + n * 16 + fr;
            float bv = (EPI >= 1) ? bias[col] : 0.f;
#pragma unroll
            for (int j = 0; j < 4; j++) {
                size_t row = (size_t)(m0 + wm + m * 16 + g * 4 + j);
                float v = acc[m][n][j] + bv;
                if (EPI == 1) v = fmaxf(v, 0.f);
                if (EPI == 2) {
                    v += bf2f(res[row * 256 + col]);
                    ((float*)Cp)[row * ldc + col] = v;
                } else {
                    ((ushort_t*)Cp)[row * ldc + col] = f2bf(v);
                }
            }
        }
}

// ---------------------------------------------------------------------------
// Kernel 4: V transpose + PV-fragment permutation.
//   vt[bh][hd][slot] = V[b, key, h, hd]  with  key = pi(slot):
//   within each 32-key chunk, slot g*8+i  <-  key (i<4 ? g*4+i : 16+g*4+i-4).
// ---------------------------------------------------------------------------
__global__ __launch_bounds__(256) void vtrans(const ushort_t* __restrict__ qkv,
                                              ushort_t* __restrict__ vt) {
    __shared__ ushort_t tile[128][40];  // padded rows
    int bh = blockIdx.x >> 3, sb = blockIdx.x & 7;
    int b = bh >> 3, h = bh & 7;
    int t = threadIdx.x;
    int s0 = sb * 128;
#pragma unroll
    for (int i = 0; i < 2; i++) {
        int s = i * 64 + (t >> 2);
        int hd0 = (t & 3) * 8;
        short8 v = *(const short8*)(qkv + ((size_t)b * SEQ + s0 + s) * 768 + 512 +
                                    h * 32 + hd0);
        *(short8*)&tile[s][hd0] = v;
    }
    __syncthreads();
    int hd = t >> 3, c0 = (t & 7) * 16;
    short8 o0, o1;
#pragma unroll
    for (int i = 0; i < 8; i++) {
        int d = c0 + i, p = d & 31, gg = p >> 3, ii = p & 7;
        int src = (d & ~31) + (ii < 4 ? gg * 4 + ii : 16 + gg * 4 + ii - 4);
        o0[i] = (short)tile[src][hd];
    }
#pragma unroll
    for (int i = 0; i < 8; i++) {
        int d = c0 + 8 + i, p = d & 31, gg = p >> 3, ii = p & 7;
        int src = (d & ~31) + (ii < 4 ? gg * 4 + ii : 16 + gg * 4 + ii - 4);
        o1[i] = (short)tile[src][hd];
    }
    ushort_t* dst = vt + (size_t)bh * 32768 + (size_t)hd * 1024 + s0 + c0;
    *(short8*)dst = o0;
    *(short8*)(dst + 8) = o1;
}

// ---------------------------------------------------------------------------
// Kernel 5: flash attention, swapped-QK^T, zero LDS, software-pipelined.
// KVBLK=64 (register-budget: s[4][2]+kreg[4]+vreg[2][2] keeps VGPR<128 so
// 4 waves/SIMD stay resident — R3's KVBLK=128 hit 136 VGPR -> 11% occupancy).
// Per iter: V loads -> QK^T -> prefetch next K -> tree softmax -> PV.
// XCD swizzle groups the 8 q-tile blocks of one (b,h) onto one XCD.
// ---------------------------------------------------------------------------
__global__ __launch_bounds__(256, 4) void attn_kernel(
    const ushort_t* __restrict__ qkv, const ushort_t* __restrict__ vt,
    ushort_t* __restrict__ ctx) {
    int cpx = gridDim.x >> 3;
    int wgid = (blockIdx.x & 7) * cpx + (blockIdx.x >> 3);
    int bh = wgid >> 3, qt = wgid & 7;
    int b = bh >> 3, h = bh & 7;
    int tid = threadIdx.x, wid = tid >> 6, lane = tid & 63;
    int fr = lane & 15, g = lane >> 4;
    int q0 = qt * 128 + wid * 32;
    const ushort_t* qbase = qkv + (size_t)b * SEQ * 768;
    const ushort_t* vbase = vt + (size_t)bh * 32768;

    // Q fragments (B operand of swapped QK^T); Q pre-scaled by log2(e)
    short8 qb[2];
#pragma unroll
    for (int m = 0; m < 2; m++)
        qb[m] = *(const short8*)(qbase + (size_t)(q0 + m * 16 + fr) * 768 +
                                 h * 32 + g * 8);

    f32x4 acc[2][2];
    const f32x4 fz = {0.f, 0.f, 0.f, 0.f};
#pragma unroll
    for (int m = 0; m < 2; m++)
#pragma unroll
        for (int n = 0; n < 2; n++) acc[m][n] = fz;
    float mrun[2] = {-1e30f, -1e30f};
    float lrun[2] = {0.f, 0.f};

    // per-lane K base (row = kv + n*16 + fr), V bases (rows fr and 16+fr)
    const ushort_t* kb_base = qbase + 256 + h * 32 + g * 8 + (size_t)fr * 768;
    const ushort_t* vp0 = vbase + (size_t)fr * 1024 + g * 8;
    const ushort_t* vp1 = vbase + (size_t)(16 + fr) * 1024 + g * 8;

    // prefetch first K tile (64 keys = 4 fragments)
    short8 kreg[4];
#pragma unroll
    for (int n = 0; n < 4; n++)
        kreg[n] = *(const short8*)(kb_base + (size_t)(n * 16) * 768);

    for (int kv = 0; kv < SEQ; kv += 64) {
        // ---- issue V loads for this tile (in flight through QK^T + softmax)
        short8 vreg[2][2];
#pragma unroll
        for (int kk = 0; kk < 2; kk++) {
            vreg[kk][0] = *(const short8*)(vp0 + kv + kk * 32);
            vreg[kk][1] = *(const short8*)(vp1 + kv + kk * 32);
        }

        // ---- scores (log2 domain): s[n][m][j] = S[key=n*16+g*4+j][q=m*16+fr]
        f32x4 s[4][2];
#pragma unroll
        for (int n = 0; n < 4; n++)
#pragma unroll
            for (int m = 0; m < 2; m++)
                s[n][m] = __builtin_amdgcn_mfma_f32_16x16x32_bf16(kreg[n], qb[m],
                                                                  fz, 0, 0, 0);

        // ---- prefetch next K tile (completes during softmax + PV)
        if (kv + 64 < SEQ) {
#pragma unroll
            for (int n = 0; n < 4; n++)
                kreg[n] = *(const short8*)(kb_base +
                                           (size_t)(kv + 64 + n * 16) * 768);
        }

        // ---- row max, pairwise trees (one q-row per lane, per m)
        float mx[2];
#pragma unroll
        for (int m = 0; m < 2; m++) {
            float t[4];
#pragma unroll
            for (int n = 0; n < 4; n++)
                t[n] = fmaxf(fmaxf(s[n][m][0], s[n][m][1]),
                             fmaxf(s[n][m][2], s[n][m][3]));
            mx[m] = fmaxf(fmaxf(t[0], t[1]), fmaxf(t[2], t[3]));
        }
#pragma unroll
        for (int m = 0; m < 2; m++) {
            mx[m] = fmaxf(mx[m], __shfl_xor(mx[m], 16));
            mx[m] = fmaxf(mx[m], __shfl_xor(mx[m], 32));
        }

        // ---- deferred-max: rescale only when a row max grew by >11.5 (log2)
        bool ok = (mx[0] - mrun[0] <= 11.5f) && (mx[1] - mrun[1] <= 11.5f);
        if (!__all(ok)) {
#pragma unroll
            for (int m = 0; m < 2; m++) {
                float mnew = fmaxf(mrun[m], mx[m]);
                float scl = exp2_fast(mrun[m] - mnew);
#pragma unroll
                for (int j = 0; j < 4; j++) {
                    float sj = __shfl(scl, g * 4 + j);
                    acc[m][0][j] *= sj;
                    acc[m][1][j] *= sj;
                }
                lrun[m] *= scl;   // lrun rows match lane rows (q = fr)
                mrun[m] = mnew;
            }
        }

        // ---- exp + row-sum trees
#pragma unroll
        for (int m = 0; m < 2; m++) {
            float r[4];
#pragma unroll
            for (int n = 0; n < 4; n++) {
                float p0 = exp2_fast(s[n][m][0] - mrun[m]);
                float p1 = exp2_fast(s[n][m][1] - mrun[m]);
                float p2 = exp2_fast(s[n][m][2] - mrun[m]);
                float p3 = exp2_fast(s[n][m][3] - mrun[m]);
                s[n][m][0] = p0; s[n][m][1] = p1;
                s[n][m][2] = p2; s[n][m][3] = p3;
                r[n] = (p0 + p1) + (p2 + p3);
            }
            float sum = (r[0] + r[1]) + (r[2] + r[3]);
            sum += __shfl_xor(sum, 16);
            sum += __shfl_xor(sum, 32);
            lrun[m] += sum;
        }

        // ---- PV: P packs in-lane into A-fragment (V rows pre-permuted)
#pragma unroll
        for (int kk = 0; kk < 2; kk++) {
#pragma unroll
            for (int m = 0; m < 2; m++) {
                union { short8 s8; uint32_t u[4]; } pa;
                asm("v_cvt_pk_bf16_f32 %0, %1, %2"
                    : "=v"(pa.u[0])
                    : "v"(s[2 * kk][m][0]), "v"(s[2 * kk][m][1]));
                asm("v_cvt_pk_bf16_f32 %0, %1, %2"
                    : "=v"(pa.u[1])
                    : "v"(s[2 * kk][m][2]), "v"(s[2 * kk][m][3]));
                asm("v_cvt_pk_bf16_f32 %0, %1, %2"
                    : "=v"(pa.u[2])
                    : "v"(s[2 * kk + 1][m][0]), "v"(s[2 * kk + 1][m][1]));
                asm("v_cvt_pk_bf16_f32 %0, %1, %2"
                    : "=v"(pa.u[3])
                    : "v"(s[2 * kk + 1][m][2]), "v"(s[2 * kk + 1][m][3]));
#pragma unroll
                for (int n = 0; n < 2; n++)
                    acc[m][n] = __builtin_amdgcn_mfma_f32_16x16x32_bf16(
                        pa.s8, vreg[kk][n], acc[m][n], 0, 0, 0);
            }
        }
    }

    // ---- epilogue: lane (fr,g) holds ctx[q=m*16+g*4+j][hd=n*16+fr]
#pragma unroll
    for (int m = 0; m < 2; m++)
#pragma unroll
        for (int j = 0; j < 4; j++) {
            float lr = __shfl(lrun[m], g * 4 + j);
            float inv = 1.f / lr;
#pragma unroll
            for (int n = 0; n < 2; n++) {
                size_t row = (size_t)b * SEQ + q0 + m * 16 + g * 4 + j;
                ctx[row * 256 + h * 32 + n * 16 + fr] =
                    f2bf(acc[m][n][j] * inv);
            }
        }
}

// ---------------------------------------------------------------------------
extern "C" void kernel_launch(void* const* d_in, const int* in_sizes, int n_in,
                              void* d_out, int out_size, void* d_ws,
                              size_t ws_size, hipStream_t stream) {
    const float* x   = (const float*)d_in[0];
    const float* wq  = (const float*)d_in[1];
    const float* wk  = (const float*)d_in[2];
    const float* wv  = (const float*)d_in[3];
    const float* g1  = (const float*)d_in[4];
    const float* be1 = (const float*)d_in[5];
    const float* g2  = (const float*)d_in[6];
    const float* be2 = (const float*)d_in[7];
    const float* wf1 = (const float*)d_in[8];
    const float* bf1 = (const float*)d_in[9];
    const float* wf2 = (const float*)d_in[10];
    const float* bf2 = (const float*)d_in[11];

    char* ws = (char*)d_ws;
    const size_t SZ16M = (size_t)ROWS * 256 * 2;  // 16 MiB
    ushort_t* wqkvT = (ushort_t*)(ws);                      // 768*256*2
    ushort_t* wf1T  = (ushort_t*)(ws + 393216);
    ushort_t* wf2T  = (ushort_t*)(ws + 524288);
    ushort_t* xn    = (ushort_t*)(ws + 655360);             // 16 MiB (reused as h)
    ushort_t* qkvb  = (ushort_t*)(ws + 655360 + SZ16M);     // 48 MiB
    ushort_t* vtb   = (ushort_t*)(ws + 655360 + SZ16M + (size_t)ROWS * 768 * 2);
    ushort_t* ctxb  = (ushort_t*)((char*)vtb + SZ16M);
    ushort_t* ab    = (ushort_t*)((char*)ctxb + SZ16M);
    ushort_t* hb    = xn;  // xn dead after QKV GEMM

    prep_weights<<<dim3(1280), dim3(256), 0, stream>>>(wq, wk, wv, wf1, wf2,
                                                       wqkvT, wf1T, wf2T);
    ln_kernel<0><<<dim3(ROWS / 4), dim3(256), 0, stream>>>(x, nullptr, g1, be1,
                                                           xn);
    gemm_bt<0><<<dim3(256 * 6), dim3(256), 0, stream>>>(xn, wqkvT, (void*)qkvb,
                                                        nullptr, nullptr, 6, 768);
    vtrans<<<dim3(2048), dim3(256), 0, stream>>>(qkvb, vtb);
    attn_kernel<<<dim3(2048), dim3(256), 0, stream>>>(qkvb, vtb, ctxb);
    ln_kernel<1><<<dim3(ROWS / 4), dim3(256), 0, stream>>>(x, ctxb, g2, be2, ab);
    gemm_bt<1><<<dim3(256 * 2), dim3(256), 0, stream>>>(ab, wf1T, (void*)hb, bf1,
                                                        nullptr, 2, 256);
    gemm_bt<2><<<dim3(256 * 2), dim3(256), 0, stream>>>(hb, wf2T, d_out, bf2, ab,
                                                        2, 256);
}

// Round 5
// 199.844 us; speedup vs baseline: 1.2033x; 1.0043x over previous
//
#include <hip/hip_runtime.h>
#include <stdint.h>

typedef unsigned short ushort_t;
typedef __attribute__((ext_vector_type(8))) short short8;
typedef __attribute__((ext_vector_type(4))) float f32x4;
typedef __attribute__((ext_vector_type(4))) unsigned short ushort4v;

#define NBATCH 32
#define SEQ 1024
#define DIM 256
#define NH 8
#define ROWS (NBATCH * SEQ)   // 32768

__device__ __forceinline__ ushort_t f2bf(float f) {
    uint32_t u = __float_as_uint(f);
    u += 0x7fffu + ((u >> 16) & 1u);   // round-to-nearest-even
    return (ushort_t)(u >> 16);
}
__device__ __forceinline__ float bf2f(ushort_t h) {
    return __uint_as_float(((uint32_t)h) << 16);
}
__device__ __forceinline__ float exp2_fast(float x) {
    float r;
    asm("v_exp_f32 %0, %1" : "=v"(r) : "v"(x));
    return r;
}

typedef __attribute__((address_space(3))) void lds_void_t;
typedef const __attribute__((address_space(1))) void glob_void_t;
__device__ __forceinline__ void gld_lds16(const void* g, void* l) {
    __builtin_amdgcn_global_load_lds((glob_void_t*)g, (lds_void_t*)l, 16, 0, 0);
}

// ---------------------------------------------------------------------------
// Kernel 1: weight prep — wT[n][k] = (bf16) w[k][n] for wq|wk|wv packed, wf1, wf2
// wq additionally scaled by log2(e): attention softmax runs in exp2 domain.
// ---------------------------------------------------------------------------
__global__ __launch_bounds__(256) void prep_weights(
    const float* __restrict__ wq, const float* __restrict__ wk,
    const float* __restrict__ wv, const float* __restrict__ wf1,
    const float* __restrict__ wf2, ushort_t* __restrict__ wqkvT,
    ushort_t* __restrict__ wf1T, ushort_t* __restrict__ wf2T) {
    int n = blockIdx.x;
    int k = threadIdx.x;
    if (n < 768) {
        const float* w = (n < 256) ? wq : (n < 512 ? wk : wv);
        int nn = n & 255;
        float v = w[k * 256 + nn];
        if (n < 256) v *= 1.4426950408889634f;  // log2(e) fold for exp2 softmax
        wqkvT[n * 256 + k] = f2bf(v);
    } else if (n < 1024) {
        int nn = n - 768;
        wf1T[nn * 256 + k] = f2bf(wf1[k * 256 + nn]);
    } else {
        int nn = n - 1024;
        wf2T[nn * 256 + k] = f2bf(wf2[k * 256 + nn]);
    }
}

// ---------------------------------------------------------------------------
// Kernel 2/6: LayerNorm (one wave per 256-elem row), optional +ctx residual
// ---------------------------------------------------------------------------
template <int ADD_CTX>
__global__ __launch_bounds__(256) void ln_kernel(
    const float* __restrict__ x, const ushort_t* __restrict__ ctx,
    const float* __restrict__ g, const float* __restrict__ beta,
    ushort_t* __restrict__ out) {
    int wid = threadIdx.x >> 6, lane = threadIdx.x & 63;
    size_t row = (size_t)blockIdx.x * 4 + wid;
    size_t base = row * 256 + lane * 4;
    float4 v = *(const float4*)(x + base);
    if (ADD_CTX) {
        ushort4v c = *(const ushort4v*)(ctx + base);
        v.x += bf2f(c[0]); v.y += bf2f(c[1]);
        v.z += bf2f(c[2]); v.w += bf2f(c[3]);
    }
    float s  = v.x + v.y + v.z + v.w;
    float s2 = v.x * v.x + v.y * v.y + v.z * v.z + v.w * v.w;
#pragma unroll
    for (int msk = 1; msk < 64; msk <<= 1) {
        s  += __shfl_xor(s, msk);
        s2 += __shfl_xor(s2, msk);
    }
    float mu  = s * (1.f / 256.f);
    float var = s2 * (1.f / 256.f) - mu * mu;
    float rs  = rsqrtf(var + 1e-5f);
    const float4 gv = *(const float4*)(g + lane * 4);
    const float4 bv = *(const float4*)(beta + lane * 4);
    ushort4v o;
    o[0] = f2bf((v.x - mu) * rs * gv.x + bv.x);
    o[1] = f2bf((v.y - mu) * rs * gv.y + bv.y);
    o[2] = f2bf((v.z - mu) * rs * gv.z + bv.z);
    o[3] = f2bf((v.w - mu) * rs * gv.w + bv.w);
    *(ushort4v*)(out + base) = o;
}

// ---------------------------------------------------------------------------
// Kernels 3/7/8: GEMM C[M x N] = A[M x 256] @ B^T[N x 256]^T   (bf16, fp32 acc)
// XCD-aware block swizzle (grid % 8 == 0 for all call sites).
// ---------------------------------------------------------------------------
template <int EPI>
__global__ __launch_bounds__(256) void gemm_bt(
    const ushort_t* __restrict__ A, const ushort_t* __restrict__ B,
    void* __restrict__ Cp, const float* __restrict__ bias,
    const ushort_t* __restrict__ res, int nbn, int ldc) {
    __shared__ ushort_t lds_a[4096];  // [128][32]
    __shared__ ushort_t lds_b[4096];  // [128][32] (rows = output cols)
    int cpx = gridDim.x >> 3;
    int blk = (blockIdx.x & 7) * cpx + (blockIdx.x >> 3);
    int bn = blk % nbn, bm = blk / nbn;
    int m0 = bm * 128, n0 = bn * 128;
    int tid = threadIdx.x, wid = tid >> 6, lane = tid & 63;
    int fr = lane & 15, g = lane >> 4;
    int wm = (wid >> 1) * 64, wn = (wid & 1) * 64;

    f32x4 acc[4][4];
    const f32x4 fz = {0.f, 0.f, 0.f, 0.f};
#pragma unroll
    for (int m = 0; m < 4; m++)
#pragma unroll
        for (int n = 0; n < 4; n++) acc[m][n] = fz;

    for (int kt = 0; kt < 256; kt += 32) {
#pragma unroll
        for (int i = 0; i < 2; i++) {
            const ushort_t* as =
                A + (size_t)(m0 + i * 64 + (tid >> 2)) * 256 + kt + (tid & 3) * 8;
            gld_lds16(as, &lds_a[i * 2048 + wid * 512]);
            const ushort_t* bs =
                B + (size_t)(n0 + i * 64 + (tid >> 2)) * 256 + kt + (tid & 3) * 8;
            gld_lds16(bs, &lds_b[i * 2048 + wid * 512]);
        }
        __syncthreads();
        short8 af[4], bfr[4];
#pragma unroll
        for (int m = 0; m < 4; m++)
            af[m] = *(const short8*)&lds_a[(wm + m * 16 + fr) * 32 + g * 8];
#pragma unroll
        for (int n = 0; n < 4; n++)
            bfr[n] = *(const short8*)&lds_b[(wn + n * 16 + fr) * 32 + g * 8];
#pragma unroll
        for (int m = 0; m < 4; m++)
#pragma unroll
            for (int n = 0; n < 4; n++)
                acc[m][n] = __builtin_amdgcn_mfma_f32_16x16x32_bf16(
                    af[m], bfr[n], acc[m][n], 0, 0, 0);
        __syncthreads();
    }

#pragma unroll
    for (int m = 0; m < 4; m++)
#pragma unroll
        for (int n = 0; n < 4; n++) {
            int col = n0 + wn + n * 16 + fr;
            float bv = (EPI >= 1) ? bias[col] : 0.f;
#pragma unroll
            for (int j = 0; j < 4; j++) {
                size_t row = (size_t)(m0 + wm + m * 16 + g * 4 + j);
                float v = acc[m][n][j] + bv;
                if (EPI == 1) v = fmaxf(v, 0.f);
                if (EPI == 2) {
                    v += bf2f(res[row * 256 + col]);
                    ((float*)Cp)[row * ldc + col] = v;
                } else {
                    ((ushort_t*)Cp)[row * ldc + col] = f2bf(v);
                }
            }
        }
}

// ---------------------------------------------------------------------------
// Kernel 4: V transpose + PV-fragment permutation.
//   vt[bh][hd][slot] = V[b, key, h, hd]  with  key = pi(slot):
//   within each 32-key chunk, slot g*8+i  <-  key (i<4 ? g*4+i : 16+g*4+i-4).
// ---------------------------------------------------------------------------
__global__ __launch_bounds__(256) void vtrans(const ushort_t* __restrict__ qkv,
                                              ushort_t* __restrict__ vt) {
    __shared__ ushort_t tile[128][40];  // padded rows
    int bh = blockIdx.x >> 3, sb = blockIdx.x & 7;
    int b = bh >> 3, h = bh & 7;
    int t = threadIdx.x;
    int s0 = sb * 128;
#pragma unroll
    for (int i = 0; i < 2; i++) {
        int s = i * 64 + (t >> 2);
        int hd0 = (t & 3) * 8;
        short8 v = *(const short8*)(qkv + ((size_t)b * SEQ + s0 + s) * 768 + 512 +
                                    h * 32 + hd0);
        *(short8*)&tile[s][hd0] = v;
    }
    __syncthreads();
    int hd = t >> 3, c0 = (t & 7) * 16;
    short8 o0, o1;
#pragma unroll
    for (int i = 0; i < 8; i++) {
        int d = c0 + i, p = d & 31, gg = p >> 3, ii = p & 7;
        int src = (d & ~31) + (ii < 4 ? gg * 4 + ii : 16 + gg * 4 + ii - 4);
        o0[i] = (short)tile[src][hd];
    }
#pragma unroll
    for (int i = 0; i < 8; i++) {
        int d = c0 + 8 + i, p = d & 31, gg = p >> 3, ii = p & 7;
        int src = (d & ~31) + (ii < 4 ? gg * 4 + ii : 16 + gg * 4 + ii - 4);
        o1[i] = (short)tile[src][hd];
    }
    ushort_t* dst = vt + (size_t)bh * 32768 + (size_t)hd * 1024 + s0 + c0;
    *(short8*)dst = o0;
    *(short8*)(dst + 8) = o1;
}

// ---------------------------------------------------------------------------
// Kernel 5: flash attention, swapped-QK^T, zero LDS, branch-free & shfl-free.
// No max subtraction: scores (log2 domain) are bounded ~±60 << 127, so
// exp2(s) and its row sums stay comfortably inside fp32 range; softmax is
// shift-invariant and bf16 P keeps the same RELATIVE precision either way.
// Row sums come from an extra ones-column PV MFMA (asum), which lands in the
// same D-layout as acc -> per-lane epilogue, no cross-lane ops anywhere.
// Per iter: V loads -> QK^T -> prefetch next K -> exp2+pack -> PV(+sum).
// ---------------------------------------------------------------------------
__global__ __launch_bounds__(256, 4) void attn_kernel(
    const ushort_t* __restrict__ qkv, const ushort_t* __restrict__ vt,
    ushort_t* __restrict__ ctx) {
    int cpx = gridDim.x >> 3;
    int wgid = (blockIdx.x & 7) * cpx + (blockIdx.x >> 3);
    int bh = wgid >> 3, qt = wgid & 7;
    int b = bh >> 3, h = bh & 7;
    int tid = threadIdx.x, wid = tid >> 6, lane = tid & 63;
    int fr = lane & 15, g = lane >> 4;
    int q0 = qt * 128 + wid * 32;
    const ushort_t* qbase = qkv + (size_t)b * SEQ * 768;
    const ushort_t* vbase = vt + (size_t)bh * 32768;

    // Q fragments (B operand of swapped QK^T); Q pre-scaled by log2(e)
    short8 qb[2];
#pragma unroll
    for (int m = 0; m < 2; m++)
        qb[m] = *(const short8*)(qbase + (size_t)(q0 + m * 16 + fr) * 768 +
                                 h * 32 + g * 8);

    f32x4 acc[2][2], asum[2];
    const f32x4 fz = {0.f, 0.f, 0.f, 0.f};
#pragma unroll
    for (int m = 0; m < 2; m++) {
        acc[m][0] = fz;
        acc[m][1] = fz;
        asum[m] = fz;
    }
    // all-ones bf16 B-fragment for the row-sum MFMA
    short8 ones8;
#pragma unroll
    for (int i = 0; i < 8; i++) ones8[i] = (short)0x3f80;

    // per-lane K base (row = kv + n*16 + fr), V bases (rows fr and 16+fr)
    const ushort_t* kb_base = qbase + 256 + h * 32 + g * 8 + (size_t)fr * 768;
    const ushort_t* vp0 = vbase + (size_t)fr * 1024 + g * 8;
    const ushort_t* vp1 = vbase + (size_t)(16 + fr) * 1024 + g * 8;

    // prefetch first K tile (64 keys = 4 fragments)
    short8 kreg[4];
#pragma unroll
    for (int n = 0; n < 4; n++)
        kreg[n] = *(const short8*)(kb_base + (size_t)(n * 16) * 768);

    for (int kv = 0; kv < SEQ; kv += 64) {
        // ---- issue V loads for this tile (in flight through QK^T + exp)
        short8 vreg[2][2];
#pragma unroll
        for (int kk = 0; kk < 2; kk++) {
            vreg[kk][0] = *(const short8*)(vp0 + kv + kk * 32);
            vreg[kk][1] = *(const short8*)(vp1 + kv + kk * 32);
        }

        // ---- scores (log2 domain): s[n][m][j] = S[key=n*16+g*4+j][q=m*16+fr]
        f32x4 s[4][2];
#pragma unroll
        for (int n = 0; n < 4; n++)
#pragma unroll
            for (int m = 0; m < 2; m++)
                s[n][m] = __builtin_amdgcn_mfma_f32_16x16x32_bf16(kreg[n], qb[m],
                                                                  fz, 0, 0, 0);

        // ---- prefetch next K tile (completes during exp + PV)
        if (kv + 64 < SEQ) {
#pragma unroll
            for (int n = 0; n < 4; n++)
                kreg[n] = *(const short8*)(kb_base +
                                           (size_t)(kv + 64 + n * 16) * 768);
        }

        // ---- P = exp2(s), pack to bf16 in-lane, PV + ones-column row-sum
#pragma unroll
        for (int kk = 0; kk < 2; kk++) {
#pragma unroll
            for (int m = 0; m < 2; m++) {
                float p0 = exp2_fast(s[2 * kk][m][0]);
                float p1 = exp2_fast(s[2 * kk][m][1]);
                float p2 = exp2_fast(s[2 * kk][m][2]);
                float p3 = exp2_fast(s[2 * kk][m][3]);
                float p4 = exp2_fast(s[2 * kk + 1][m][0]);
                float p5 = exp2_fast(s[2 * kk + 1][m][1]);
                float p6 = exp2_fast(s[2 * kk + 1][m][2]);
                float p7 = exp2_fast(s[2 * kk + 1][m][3]);
                union { short8 s8; uint32_t u[4]; } pa;
                asm("v_cvt_pk_bf16_f32 %0, %1, %2"
                    : "=v"(pa.u[0]) : "v"(p0), "v"(p1));
                asm("v_cvt_pk_bf16_f32 %0, %1, %2"
                    : "=v"(pa.u[1]) : "v"(p2), "v"(p3));
                asm("v_cvt_pk_bf16_f32 %0, %1, %2"
                    : "=v"(pa.u[2]) : "v"(p4), "v"(p5));
                asm("v_cvt_pk_bf16_f32 %0, %1, %2"
                    : "=v"(pa.u[3]) : "v"(p6), "v"(p7));
                acc[m][0] = __builtin_amdgcn_mfma_f32_16x16x32_bf16(
                    pa.s8, vreg[kk][0], acc[m][0], 0, 0, 0);
                acc[m][1] = __builtin_amdgcn_mfma_f32_16x16x32_bf16(
                    pa.s8, vreg[kk][1], acc[m][1], 0, 0, 0);
                asum[m] = __builtin_amdgcn_mfma_f32_16x16x32_bf16(
                    pa.s8, ones8, asum[m], 0, 0, 0);
            }
        }
    }

    // ---- epilogue: lane (fr,g) holds ctx[q=m*16+g*4+j][hd=n*16+fr];
    //      asum[m][j] is the matching row sum (same D layout) -> no shfl.
#pragma unroll
    for (int m = 0; m < 2; m++)
#pragma unroll
        for (int j = 0; j < 4; j++) {
            float inv = 1.f / asum[m][j];
#pragma unroll
            for (int n = 0; n < 2; n++) {
                size_t row = (size_t)b * SEQ + q0 + m * 16 + g * 4 + j;
                ctx[row * 256 + h * 32 + n * 16 + fr] =
                    f2bf(acc[m][n][j] * inv);
            }
        }
}

// ---------------------------------------------------------------------------
extern "C" void kernel_launch(void* const* d_in, const int* in_sizes, int n_in,
                              void* d_out, int out_size, void* d_ws,
                              size_t ws_size, hipStream_t stream) {
    const float* x   = (const float*)d_in[0];
    const float* wq  = (const float*)d_in[1];
    const float* wk  = (const float*)d_in[2];
    const float* wv  = (const float*)d_in[3];
    const float* g1  = (const float*)d_in[4];
    const float* be1 = (const float*)d_in[5];
    const float* g2  = (const float*)d_in[6];
    const float* be2 = (const float*)d_in[7];
    const float* wf1 = (const float*)d_in[8];
    const float* bf1 = (const float*)d_in[9];
    const float* wf2 = (const float*)d_in[10];
    const float* bf2 = (const float*)d_in[11];

    char* ws = (char*)d_ws;
    const size_t SZ16M = (size_t)ROWS * 256 * 2;  // 16 MiB
    ushort_t* wqkvT = (ushort_t*)(ws);                      // 768*256*2
    ushort_t* wf1T  = (ushort_t*)(ws + 393216);
    ushort_t* wf2T  = (ushort_t*)(ws + 524288);
    ushort_t* xn    = (ushort_t*)(ws + 655360);             // 16 MiB (reused as h)
    ushort_t* qkvb  = (ushort_t*)(ws + 655360 + SZ16M);     // 48 MiB
    ushort_t* vtb   = (ushort_t*)(ws + 655360 + SZ16M + (size_t)ROWS * 768 * 2);
    ushort_t* ctxb  = (ushort_t*)((char*)vtb + SZ16M);
    ushort_t* ab    = (ushort_t*)((char*)ctxb + SZ16M);
    ushort_t* hb    = xn;  // xn dead after QKV GEMM

    prep_weights<<<dim3(1280), dim3(256), 0, stream>>>(wq, wk, wv, wf1, wf2,
                                                       wqkvT, wf1T, wf2T);
    ln_kernel<0><<<dim3(ROWS / 4), dim3(256), 0, stream>>>(x, nullptr, g1, be1,
                                                           xn);
    gemm_bt<0><<<dim3(256 * 6), dim3(256), 0, stream>>>(xn, wqkvT, (void*)qkvb,
                                                        nullptr, nullptr, 6, 768);
    vtrans<<<dim3(2048), dim3(256), 0, stream>>>(qkvb, vtb);
    attn_kernel<<<dim3(2048), dim3(256), 0, stream>>>(qkvb, vtb, ctxb);
    ln_kernel<1><<<dim3(ROWS / 4), dim3(256), 0, stream>>>(x, ctxb, g2, be2, ab);
    gemm_bt<1><<<dim3(256 * 2), dim3(256), 0, stream>>>(ab, wf1T, (void*)hb, bf1,
                                                        nullptr, 2, 256);
    gemm_bt<2><<<dim3(256 * 2), dim3(256), 0, stream>>>(hb, wf2T, d_out, bf2, ab,
                                                        2, 256);
}

// Round 9
// 194.654 us; speedup vs baseline: 1.2354x; 1.0267x over previous
//
#include <hip/hip_runtime.h>
#include <stdint.h>

typedef unsigned short ushort_t;
typedef __attribute__((ext_vector_type(8))) short short8;
typedef __attribute__((ext_vector_type(4))) float f32x4;
typedef __attribute__((ext_vector_type(4))) unsigned short ushort4v;

#define NBATCH 32
#define SEQ 1024
#define DIM 256
#define NH 8
#define ROWS (NBATCH * SEQ)   // 32768

__device__ __forceinline__ ushort_t f2bf(float f) {
    uint32_t u = __float_as_uint(f);
    u += 0x7fffu + ((u >> 16) & 1u);   // round-to-nearest-even
    return (ushort_t)(u >> 16);
}
__device__ __forceinline__ float bf2f(ushort_t h) {
    return __uint_as_float(((uint32_t)h) << 16);
}
__device__ __forceinline__ float exp2_fast(float x) {
    float r;
    asm("v_exp_f32 %0, %1" : "=v"(r) : "v"(x));
    return r;
}

typedef __attribute__((address_space(3))) void lds_void_t;
typedef const __attribute__((address_space(1))) void glob_void_t;
__device__ __forceinline__ void gld_lds16(const void* g, void* l) {
    __builtin_amdgcn_global_load_lds((glob_void_t*)g, (lds_void_t*)l, 16, 0, 0);
}

// ---------------------------------------------------------------------------
// Kernel 1: weight prep — wT[n][k] = (bf16) w[k][n] for wq|wk|wv packed, wf1, wf2
// wq additionally scaled by log2(e): attention softmax runs in exp2 domain.
// ---------------------------------------------------------------------------
__global__ __launch_bounds__(256) void prep_weights(
    const float* __restrict__ wq, const float* __restrict__ wk,
    const float* __restrict__ wv, const float* __restrict__ wf1,
    const float* __restrict__ wf2, ushort_t* __restrict__ wqkvT,
    ushort_t* __restrict__ wf1T, ushort_t* __restrict__ wf2T) {
    int n = blockIdx.x;
    int k = threadIdx.x;
    if (n < 768) {
        const float* w = (n < 256) ? wq : (n < 512 ? wk : wv);
        int nn = n & 255;
        float v = w[k * 256 + nn];
        if (n < 256) v *= 1.4426950408889634f;  // log2(e) fold for exp2 softmax
        wqkvT[n * 256 + k] = f2bf(v);
    } else if (n < 1024) {
        int nn = n - 768;
        wf1T[nn * 256 + k] = f2bf(wf1[k * 256 + nn]);
    } else {
        int nn = n - 1024;
        wf2T[nn * 256 + k] = f2bf(wf2[k * 256 + nn]);
    }
}

// ---------------------------------------------------------------------------
// Kernel 2/6: LayerNorm (one wave per 256-elem row), optional +ctx residual
// ---------------------------------------------------------------------------
template <int ADD_CTX>
__global__ __launch_bounds__(256) void ln_kernel(
    const float* __restrict__ x, const ushort_t* __restrict__ ctx,
    const float* __restrict__ g, const float* __restrict__ beta,
    ushort_t* __restrict__ out) {
    int wid = threadIdx.x >> 6, lane = threadIdx.x & 63;
    size_t row = (size_t)blockIdx.x * 4 + wid;
    size_t base = row * 256 + lane * 4;
    float4 v = *(const float4*)(x + base);
    if (ADD_CTX) {
        ushort4v c = *(const ushort4v*)(ctx + base);
        v.x += bf2f(c[0]); v.y += bf2f(c[1]);
        v.z += bf2f(c[2]); v.w += bf2f(c[3]);
    }
    float s  = v.x + v.y + v.z + v.w;
    float s2 = v.x * v.x + v.y * v.y + v.z * v.z + v.w * v.w;
#pragma unroll
    for (int msk = 1; msk < 64; msk <<= 1) {
        s  += __shfl_xor(s, msk);
        s2 += __shfl_xor(s2, msk);
    }
    float mu  = s * (1.f / 256.f);
    float var = s2 * (1.f / 256.f) - mu * mu;
    float rs  = rsqrtf(var + 1e-5f);
    const float4 gv = *(const float4*)(g + lane * 4);
    const float4 bv = *(const float4*)(beta + lane * 4);
    ushort4v o;
    o[0] = f2bf((v.x - mu) * rs * gv.x + bv.x);
    o[1] = f2bf((v.y - mu) * rs * gv.y + bv.y);
    o[2] = f2bf((v.z - mu) * rs * gv.z + bv.z);
    o[3] = f2bf((v.w - mu) * rs * gv.w + bv.w);
    *(ushort4v*)(out + base) = o;
}

// ---------------------------------------------------------------------------
// Kernels 3/7/8: GEMM C[M x N] = A[M x 256] @ B^T[N x 256]^T   (bf16, fp32 acc)
// XCD-aware block swizzle (grid % 8 == 0 for all call sites).
// EPI: 0 = plain -> bf16 C
//      1 = +bias, relu -> bf16 (FFN1)
//      2 = +bias, +res -> f32  (FFN2 -> d_out)
//      3 = QKV + fused V-relayout: cols<512 -> qkv bf16; cols>=512 -> packed
//          ushort4 store into vt[bh][hd][slot] with slot = sigma(key)
//          (sigma = inverse of attn's PV slot permutation pi; j=0..3 keys map
//           to consecutive slots since key base is 0 mod 4).
// ---------------------------------------------------------------------------
template <int EPI>
__global__ __launch_bounds__(256) void gemm_bt(
    const ushort_t* __restrict__ A, const ushort_t* __restrict__ B,
    void* __restrict__ Cp, const float* __restrict__ bias,
    const ushort_t* __restrict__ res, ushort_t* __restrict__ vtout, int nbn,
    int ldc) {
    __shared__ ushort_t lds_a[4096];  // [128][32]
    __shared__ ushort_t lds_b[4096];  // [128][32] (rows = output cols)
    int cpx = gridDim.x >> 3;
    int blk = (blockIdx.x & 7) * cpx + (blockIdx.x >> 3);
    int bn = blk % nbn, bm = blk / nbn;
    int m0 = bm * 128, n0 = bn * 128;
    int tid = threadIdx.x, wid = tid >> 6, lane = tid & 63;
    int fr = lane & 15, g = lane >> 4;
    int wm = (wid >> 1) * 64, wn = (wid & 1) * 64;

    f32x4 acc[4][4];
    const f32x4 fz = {0.f, 0.f, 0.f, 0.f};
#pragma unroll
    for (int m = 0; m < 4; m++)
#pragma unroll
        for (int n = 0; n < 4; n++) acc[m][n] = fz;

    for (int kt = 0; kt < 256; kt += 32) {
#pragma unroll
        for (int i = 0; i < 2; i++) {
            const ushort_t* as =
                A + (size_t)(m0 + i * 64 + (tid >> 2)) * 256 + kt + (tid & 3) * 8;
            gld_lds16(as, &lds_a[i * 2048 + wid * 512]);
            const ushort_t* bs =
                B + (size_t)(n0 + i * 64 + (tid >> 2)) * 256 + kt + (tid & 3) * 8;
            gld_lds16(bs, &lds_b[i * 2048 + wid * 512]);
        }
        __syncthreads();
        short8 af[4], bfr[4];
#pragma unroll
        for (int m = 0; m < 4; m++)
            af[m] = *(const short8*)&lds_a[(wm + m * 16 + fr) * 32 + g * 8];
#pragma unroll
        for (int n = 0; n < 4; n++)
            bfr[n] = *(const short8*)&lds_b[(wn + n * 16 + fr) * 32 + g * 8];
#pragma unroll
        for (int m = 0; m < 4; m++)
#pragma unroll
            for (int n = 0; n < 4; n++)
                acc[m][n] = __builtin_amdgcn_mfma_f32_16x16x32_bf16(
                    af[m], bfr[n], acc[m][n], 0, 0, 0);
        __syncthreads();
    }

#pragma unroll
    for (int m = 0; m < 4; m++)
#pragma unroll
        for (int n = 0; n < 4; n++) {
            int col = n0 + wn + n * 16 + fr;
            if (EPI == 3 && col >= 512) {
                // V column: fused transpose+permute relayout into vt.
                int hd = col & 31;
                int hh = (col >> 5) & 7;  // head
                int rowbase = m0 + wm + m * 16 + g * 4;
                int bb = rowbase >> 10;
                int key = rowbase & 1023;  // key base, multiple of 4
                int slot0 = (key & ~31) + (((key & 15) >> 2) << 3) +
                            (((key >> 4) & 1) << 2);
                ushort4v o;
                o[0] = f2bf(acc[m][n][0]);
                o[1] = f2bf(acc[m][n][1]);
                o[2] = f2bf(acc[m][n][2]);
                o[3] = f2bf(acc[m][n][3]);
                *(ushort4v*)(vtout + (size_t)(bb * 8 + hh) * 32768 +
                             (size_t)hd * 1024 + slot0) = o;
            } else {
                float bv = (EPI == 1 || EPI == 2) ? bias[col] : 0.f;
#pragma unroll
                for (int j = 0; j < 4; j++) {
                    size_t row = (size_t)(m0 + wm + m * 16 + g * 4 + j);
                    float v = acc[m][n][j] + bv;
                    if (EPI == 1) v = fmaxf(v, 0.f);
                    if (EPI == 2) {
                        v += bf2f(res[row * 256 + col]);
                        ((float*)Cp)[row * ldc + col] = v;
                    } else {
                        ((ushort_t*)Cp)[row * ldc + col] = f2bf(v);
                    }
                }
            }
        }
}

// ---------------------------------------------------------------------------
// Kernel 5: flash attention, swapped-QK^T, zero LDS, branch-free & shfl-free.
// BYTE-IDENTICAL to R5's verified kernel (R6/R7/R8 post-mortem: the
// pointer-bump + named-dbuf restructure NaN'd 3x — structure frozen).
// No max subtraction: scores (log2 domain) are bounded ~±60 << 127, so
// exp2(s) and its row sums stay comfortably inside fp32 range; softmax is
// shift-invariant and bf16 P keeps the same RELATIVE precision either way.
// Row sums come from an extra ones-column PV MFMA (asum), which lands in the
// same D-layout as acc -> per-lane epilogue, no cross-lane ops anywhere.
// Per iter: V loads -> QK^T -> prefetch next K -> exp2+pack -> PV(+sum).
// ---------------------------------------------------------------------------
__global__ __launch_bounds__(256, 4) void attn_kernel(
    const ushort_t* __restrict__ qkv, const ushort_t* __restrict__ vt,
    ushort_t* __restrict__ ctx) {
    int cpx = gridDim.x >> 3;
    int wgid = (blockIdx.x & 7) * cpx + (blockIdx.x >> 3);
    int bh = wgid >> 3, qt = wgid & 7;
    int b = bh >> 3, h = bh & 7;
    int tid = threadIdx.x, wid = tid >> 6, lane = tid & 63;
    int fr = lane & 15, g = lane >> 4;
    int q0 = qt * 128 + wid * 32;
    const ushort_t* qbase = qkv + (size_t)b * SEQ * 768;
    const ushort_t* vbase = vt + (size_t)bh * 32768;

    // Q fragments (B operand of swapped QK^T); Q pre-scaled by log2(e)
    short8 qb[2];
#pragma unroll
    for (int m = 0; m < 2; m++)
        qb[m] = *(const short8*)(qbase + (size_t)(q0 + m * 16 + fr) * 768 +
                                 h * 32 + g * 8);

    f32x4 acc[2][2], asum[2];
    const f32x4 fz = {0.f, 0.f, 0.f, 0.f};
#pragma unroll
    for (int m = 0; m < 2; m++) {
        acc[m][0] = fz;
        acc[m][1] = fz;
        asum[m] = fz;
    }
    // all-ones bf16 B-fragment for the row-sum MFMA
    short8 ones8;
#pragma unroll
    for (int i = 0; i < 8; i++) ones8[i] = (short)0x3f80;

    // per-lane K base (row = kv + n*16 + fr), V bases (rows fr and 16+fr)
    const ushort_t* kb_base = qbase + 256 + h * 32 + g * 8 + (size_t)fr * 768;
    const ushort_t* vp0 = vbase + (size_t)fr * 1024 + g * 8;
    const ushort_t* vp1 = vbase + (size_t)(16 + fr) * 1024 + g * 8;

    // prefetch first K tile (64 keys = 4 fragments)
    short8 kreg[4];
#pragma unroll
    for (int n = 0; n < 4; n++)
        kreg[n] = *(const short8*)(kb_base + (size_t)(n * 16) * 768);

    for (int kv = 0; kv < SEQ; kv += 64) {
        // ---- issue V loads for this tile (in flight through QK^T + exp)
        short8 vreg[2][2];
#pragma unroll
        for (int kk = 0; kk < 2; kk++) {
            vreg[kk][0] = *(const short8*)(vp0 + kv + kk * 32);
            vreg[kk][1] = *(const short8*)(vp1 + kv + kk * 32);
        }

        // ---- scores (log2 domain): s[n][m][j] = S[key=n*16+g*4+j][q=m*16+fr]
        f32x4 s[4][2];
#pragma unroll
        for (int n = 0; n < 4; n++)
#pragma unroll
            for (int m = 0; m < 2; m++)
                s[n][m] = __builtin_amdgcn_mfma_f32_16x16x32_bf16(kreg[n], qb[m],
                                                                  fz, 0, 0, 0);

        // ---- prefetch next K tile (completes during exp + PV)
        if (kv + 64 < SEQ) {
#pragma unroll
            for (int n = 0; n < 4; n++)
                kreg[n] = *(const short8*)(kb_base +
                                           (size_t)(kv + 64 + n * 16) * 768);
        }

        // ---- P = exp2(s), pack to bf16 in-lane, PV + ones-column row-sum
#pragma unroll
        for (int kk = 0; kk < 2; kk++) {
#pragma unroll
            for (int m = 0; m < 2; m++) {
                float p0 = exp2_fast(s[2 * kk][m][0]);
                float p1 = exp2_fast(s[2 * kk][m][1]);
                float p2 = exp2_fast(s[2 * kk][m][2]);
                float p3 = exp2_fast(s[2 * kk][m][3]);
                float p4 = exp2_fast(s[2 * kk + 1][m][0]);
                float p5 = exp2_fast(s[2 * kk + 1][m][1]);
                float p6 = exp2_fast(s[2 * kk + 1][m][2]);
                float p7 = exp2_fast(s[2 * kk + 1][m][3]);
                union { short8 s8; uint32_t u[4]; } pa;
                asm("v_cvt_pk_bf16_f32 %0, %1, %2"
                    : "=v"(pa.u[0]) : "v"(p0), "v"(p1));
                asm("v_cvt_pk_bf16_f32 %0, %1, %2"
                    : "=v"(pa.u[1]) : "v"(p2), "v"(p3));
                asm("v_cvt_pk_bf16_f32 %0, %1, %2"
                    : "=v"(pa.u[2]) : "v"(p4), "v"(p5));
                asm("v_cvt_pk_bf16_f32 %0, %1, %2"
                    : "=v"(pa.u[3]) : "v"(p6), "v"(p7));
                acc[m][0] = __builtin_amdgcn_mfma_f32_16x16x32_bf16(
                    pa.s8, vreg[kk][0], acc[m][0], 0, 0, 0);
                acc[m][1] = __builtin_amdgcn_mfma_f32_16x16x32_bf16(
                    pa.s8, vreg[kk][1], acc[m][1], 0, 0, 0);
                asum[m] = __builtin_amdgcn_mfma_f32_16x16x32_bf16(
                    pa.s8, ones8, asum[m], 0, 0, 0);
            }
        }
    }

    // ---- epilogue: lane (fr,g) holds ctx[q=m*16+g*4+j][hd=n*16+fr];
    //      asum[m][j] is the matching row sum (same D layout) -> no shfl.
#pragma unroll
    for (int m = 0; m < 2; m++)
#pragma unroll
        for (int j = 0; j < 4; j++) {
            float inv = 1.f / asum[m][j];
#pragma unroll
            for (int n = 0; n < 2; n++) {
                size_t row = (size_t)b * SEQ + q0 + m * 16 + g * 4 + j;
                ctx[row * 256 + h * 32 + n * 16 + fr] =
                    f2bf(acc[m][n][j] * inv);
            }
        }
}

// ---------------------------------------------------------------------------
extern "C" void kernel_launch(void* const* d_in, const int* in_sizes, int n_in,
                              void* d_out, int out_size, void* d_ws,
                              size_t ws_size, hipStream_t stream) {
    const float* x   = (const float*)d_in[0];
    const float* wq  = (const float*)d_in[1];
    const float* wk  = (const float*)d_in[2];
    const float* wv  = (const float*)d_in[3];
    const float* g1  = (const float*)d_in[4];
    const float* be1 = (const float*)d_in[5];
    const float* g2  = (const float*)d_in[6];
    const float* be2 = (const float*)d_in[7];
    const float* wf1 = (const float*)d_in[8];
    const float* bf1 = (const float*)d_in[9];
    const float* wf2 = (const float*)d_in[10];
    const float* bf2 = (const float*)d_in[11];

    char* ws = (char*)d_ws;
    const size_t SZ16M = (size_t)ROWS * 256 * 2;  // 16 MiB
    ushort_t* wqkvT = (ushort_t*)(ws);                      // 768*256*2
    ushort_t* wf1T  = (ushort_t*)(ws + 393216);
    ushort_t* wf2T  = (ushort_t*)(ws + 524288);
    ushort_t* xn    = (ushort_t*)(ws + 655360);             // 16 MiB (reused as h)
    ushort_t* qkvb  = (ushort_t*)(ws + 655360 + SZ16M);     // 48 MiB
    ushort_t* vtb   = (ushort_t*)(ws + 655360 + SZ16M + (size_t)ROWS * 768 * 2);
    ushort_t* ctxb  = (ushort_t*)((char*)vtb + SZ16M);
    ushort_t* ab    = (ushort_t*)((char*)ctxb + SZ16M);
    ushort_t* hb    = xn;  // xn dead after QKV GEMM

    prep_weights<<<dim3(1280), dim3(256), 0, stream>>>(wq, wk, wv, wf1, wf2,
                                                       wqkvT, wf1T, wf2T);
    ln_kernel<0><<<dim3(ROWS / 4), dim3(256), 0, stream>>>(x, nullptr, g1, be1,
                                                           xn);
    gemm_bt<3><<<dim3(256 * 6), dim3(256), 0, stream>>>(
        xn, wqkvT, (void*)qkvb, nullptr, nullptr, vtb, 6, 768);
    attn_kernel<<<dim3(2048), dim3(256), 0, stream>>>(qkvb, vtb, ctxb);
    ln_kernel<1><<<dim3(ROWS / 4), dim3(256), 0, stream>>>(x, ctxb, g2, be2, ab);
    gemm_bt<1><<<dim3(256 * 2), dim3(256), 0, stream>>>(
        ab, wf1T, (void*)hb, bf1, nullptr, nullptr, 2, 256);
    gemm_bt<2><<<dim3(256 * 2), dim3(256), 0, stream>>>(
        hb, wf2T, d_out, bf2, ab, nullptr, 2, 256);
}

// Round 10
// 194.572 us; speedup vs baseline: 1.2359x; 1.0004x over previous
//
#include <hip/hip_runtime.h>
#include <stdint.h>

typedef unsigned short ushort_t;
typedef __attribute__((ext_vector_type(8))) short short8;
typedef __attribute__((ext_vector_type(4))) float f32x4;
typedef __attribute__((ext_vector_type(4))) unsigned short ushort4v;

#define NBATCH 32
#define SEQ 1024
#define DIM 256
#define NH 8
#define ROWS (NBATCH * SEQ)   // 32768

__device__ __forceinline__ ushort_t f2bf(float f) {
    uint32_t u = __float_as_uint(f);
    u += 0x7fffu + ((u >> 16) & 1u);   // round-to-nearest-even
    return (ushort_t)(u >> 16);
}
__device__ __forceinline__ float bf2f(ushort_t h) {
    return __uint_as_float(((uint32_t)h) << 16);
}
__device__ __forceinline__ float exp2_fast(float x) {
    float r;
    asm("v_exp_f32 %0, %1" : "=v"(r) : "v"(x));
    return r;
}

typedef __attribute__((address_space(3))) void lds_void_t;
typedef const __attribute__((address_space(1))) void glob_void_t;
__device__ __forceinline__ void gld_lds16(const void* g, void* l) {
    __builtin_amdgcn_global_load_lds((glob_void_t*)g, (lds_void_t*)l, 16, 0, 0);
}

// ---------------------------------------------------------------------------
// Kernel 1: weight prep — wT[n][k] = (bf16) w[k][n] for wq|wk|wv packed, wf1, wf2
// wq additionally scaled by log2(e): attention softmax runs in exp2 domain.
// ---------------------------------------------------------------------------
__global__ __launch_bounds__(256) void prep_weights(
    const float* __restrict__ wq, const float* __restrict__ wk,
    const float* __restrict__ wv, const float* __restrict__ wf1,
    const float* __restrict__ wf2, ushort_t* __restrict__ wqkvT,
    ushort_t* __restrict__ wf1T, ushort_t* __restrict__ wf2T) {
    int n = blockIdx.x;
    int k = threadIdx.x;
    if (n < 768) {
        const float* w = (n < 256) ? wq : (n < 512 ? wk : wv);
        int nn = n & 255;
        float v = w[k * 256 + nn];
        if (n < 256) v *= 1.4426950408889634f;  // log2(e) fold for exp2 softmax
        wqkvT[n * 256 + k] = f2bf(v);
    } else if (n < 1024) {
        int nn = n - 768;
        wf1T[nn * 256 + k] = f2bf(wf1[k * 256 + nn]);
    } else {
        int nn = n - 1024;
        wf2T[nn * 256 + k] = f2bf(wf2[k * 256 + nn]);
    }
}

// ---------------------------------------------------------------------------
// Kernel 2/6: LayerNorm (one wave per 256-elem row), optional +ctx residual
// ---------------------------------------------------------------------------
template <int ADD_CTX>
__global__ __launch_bounds__(256) void ln_kernel(
    const float* __restrict__ x, const ushort_t* __restrict__ ctx,
    const float* __restrict__ g, const float* __restrict__ beta,
    ushort_t* __restrict__ out) {
    int wid = threadIdx.x >> 6, lane = threadIdx.x & 63;
    size_t row = (size_t)blockIdx.x * 4 + wid;
    size_t base = row * 256 + lane * 4;
    float4 v = *(const float4*)(x + base);
    if (ADD_CTX) {
        ushort4v c = *(const ushort4v*)(ctx + base);
        v.x += bf2f(c[0]); v.y += bf2f(c[1]);
        v.z += bf2f(c[2]); v.w += bf2f(c[3]);
    }
    float s  = v.x + v.y + v.z + v.w;
    float s2 = v.x * v.x + v.y * v.y + v.z * v.z + v.w * v.w;
#pragma unroll
    for (int msk = 1; msk < 64; msk <<= 1) {
        s  += __shfl_xor(s, msk);
        s2 += __shfl_xor(s2, msk);
    }
    float mu  = s * (1.f / 256.f);
    float var = s2 * (1.f / 256.f) - mu * mu;
    float rs  = rsqrtf(var + 1e-5f);
    const float4 gv = *(const float4*)(g + lane * 4);
    const float4 bv = *(const float4*)(beta + lane * 4);
    ushort4v o;
    o[0] = f2bf((v.x - mu) * rs * gv.x + bv.x);
    o[1] = f2bf((v.y - mu) * rs * gv.y + bv.y);
    o[2] = f2bf((v.z - mu) * rs * gv.z + bv.z);
    o[3] = f2bf((v.w - mu) * rs * gv.w + bv.w);
    *(ushort4v*)(out + base) = o;
}

// ---------------------------------------------------------------------------
// Kernels 3/7/8: GEMM C[M x N] = A[M x 256] @ B^T[N x 256]^T   (bf16, fp32 acc)
// XCD-aware block swizzle (grid % 8 == 0 for all call sites).
// EPI: 0 = plain -> bf16 C
//      1 = +bias, relu -> bf16 (FFN1)
//      2 = +bias, +res -> f32  (FFN2 -> d_out)
//      3 = QKV + fused V-relayout: cols<512 -> qkv bf16; cols>=512 -> packed
//          ushort4 store into vt[bh][hd][slot] with slot = sigma(key)
//          (sigma = inverse of attn's PV slot permutation pi; j=0..3 keys map
//           to consecutive slots since key base is 0 mod 4).
// ---------------------------------------------------------------------------
template <int EPI>
__global__ __launch_bounds__(256) void gemm_bt(
    const ushort_t* __restrict__ A, const ushort_t* __restrict__ B,
    void* __restrict__ Cp, const float* __restrict__ bias,
    const ushort_t* __restrict__ res, ushort_t* __restrict__ vtout, int nbn,
    int ldc) {
    __shared__ ushort_t lds_a[4096];  // [128][32]
    __shared__ ushort_t lds_b[4096];  // [128][32] (rows = output cols)
    int cpx = gridDim.x >> 3;
    int blk = (blockIdx.x & 7) * cpx + (blockIdx.x >> 3);
    int bn = blk % nbn, bm = blk / nbn;
    int m0 = bm * 128, n0 = bn * 128;
    int tid = threadIdx.x, wid = tid >> 6, lane = tid & 63;
    int fr = lane & 15, g = lane >> 4;
    int wm = (wid >> 1) * 64, wn = (wid & 1) * 64;

    f32x4 acc[4][4];
    const f32x4 fz = {0.f, 0.f, 0.f, 0.f};
#pragma unroll
    for (int m = 0; m < 4; m++)
#pragma unroll
        for (int n = 0; n < 4; n++) acc[m][n] = fz;

    for (int kt = 0; kt < 256; kt += 32) {
#pragma unroll
        for (int i = 0; i < 2; i++) {
            const ushort_t* as =
                A + (size_t)(m0 + i * 64 + (tid >> 2)) * 256 + kt + (tid & 3) * 8;
            gld_lds16(as, &lds_a[i * 2048 + wid * 512]);
            const ushort_t* bs =
                B + (size_t)(n0 + i * 64 + (tid >> 2)) * 256 + kt + (tid & 3) * 8;
            gld_lds16(bs, &lds_b[i * 2048 + wid * 512]);
        }
        __syncthreads();
        short8 af[4], bfr[4];
#pragma unroll
        for (int m = 0; m < 4; m++)
            af[m] = *(const short8*)&lds_a[(wm + m * 16 + fr) * 32 + g * 8];
#pragma unroll
        for (int n = 0; n < 4; n++)
            bfr[n] = *(const short8*)&lds_b[(wn + n * 16 + fr) * 32 + g * 8];
#pragma unroll
        for (int m = 0; m < 4; m++)
#pragma unroll
            for (int n = 0; n < 4; n++)
                acc[m][n] = __builtin_amdgcn_mfma_f32_16x16x32_bf16(
                    af[m], bfr[n], acc[m][n], 0, 0, 0);
        __syncthreads();
    }

#pragma unroll
    for (int m = 0; m < 4; m++)
#pragma unroll
        for (int n = 0; n < 4; n++) {
            int col = n0 + wn + n * 16 + fr;
            if (EPI == 3 && col >= 512) {
                // V column: fused transpose+permute relayout into vt.
                int hd = col & 31;
                int hh = (col >> 5) & 7;  // head
                int rowbase = m0 + wm + m * 16 + g * 4;
                int bb = rowbase >> 10;
                int key = rowbase & 1023;  // key base, multiple of 4
                int slot0 = (key & ~31) + (((key & 15) >> 2) << 3) +
                            (((key >> 4) & 1) << 2);
                ushort4v o;
                o[0] = f2bf(acc[m][n][0]);
                o[1] = f2bf(acc[m][n][1]);
                o[2] = f2bf(acc[m][n][2]);
                o[3] = f2bf(acc[m][n][3]);
                *(ushort4v*)(vtout + (size_t)(bb * 8 + hh) * 32768 +
                             (size_t)hd * 1024 + slot0) = o;
            } else {
                float bv = (EPI == 1 || EPI == 2) ? bias[col] : 0.f;
#pragma unroll
                for (int j = 0; j < 4; j++) {
                    size_t row = (size_t)(m0 + wm + m * 16 + g * 4 + j);
                    float v = acc[m][n][j] + bv;
                    if (EPI == 1) v = fmaxf(v, 0.f);
                    if (EPI == 2) {
                        v += bf2f(res[row * 256 + col]);
                        ((float*)Cp)[row * ldc + col] = v;
                    } else {
                        ((ushort_t*)Cp)[row * ldc + col] = f2bf(v);
                    }
                }
            }
        }
}

// ---------------------------------------------------------------------------
// Kernel 5: flash attention, swapped-QK^T, zero LDS, branch-free & shfl-free.
// R5's verified structure with ONE change (single-variable experiment):
// V is double-buffered one tile ahead via vnxt + statically-indexed
// copy-rotate at the loop bottom. Indexed addressing and the single
// non-unrolled loop are kept (R6/R7/R8's bumped-pointer + unrolled-A/B
// restructure NaN'd 3x; this isolates the dbuf variable alone).
// ---------------------------------------------------------------------------
__global__ __launch_bounds__(256, 4) void attn_kernel(
    const ushort_t* __restrict__ qkv, const ushort_t* __restrict__ vt,
    ushort_t* __restrict__ ctx) {
    int cpx = gridDim.x >> 3;
    int wgid = (blockIdx.x & 7) * cpx + (blockIdx.x >> 3);
    int bh = wgid >> 3, qt = wgid & 7;
    int b = bh >> 3, h = bh & 7;
    int tid = threadIdx.x, wid = tid >> 6, lane = tid & 63;
    int fr = lane & 15, g = lane >> 4;
    int q0 = qt * 128 + wid * 32;
    const ushort_t* qbase = qkv + (size_t)b * SEQ * 768;
    const ushort_t* vbase = vt + (size_t)bh * 32768;

    // Q fragments (B operand of swapped QK^T); Q pre-scaled by log2(e)
    short8 qb[2];
#pragma unroll
    for (int m = 0; m < 2; m++)
        qb[m] = *(const short8*)(qbase + (size_t)(q0 + m * 16 + fr) * 768 +
                                 h * 32 + g * 8);

    f32x4 acc[2][2], asum[2];
    const f32x4 fz = {0.f, 0.f, 0.f, 0.f};
#pragma unroll
    for (int m = 0; m < 2; m++) {
        acc[m][0] = fz;
        acc[m][1] = fz;
        asum[m] = fz;
    }
    // all-ones bf16 B-fragment for the row-sum MFMA
    short8 ones8;
#pragma unroll
    for (int i = 0; i < 8; i++) ones8[i] = (short)0x3f80;

    // per-lane K base (row = kv + n*16 + fr), V bases (rows fr and 16+fr)
    const ushort_t* kb_base = qbase + 256 + h * 32 + g * 8 + (size_t)fr * 768;
    const ushort_t* vp0 = vbase + (size_t)fr * 1024 + g * 8;
    const ushort_t* vp1 = vbase + (size_t)(16 + fr) * 1024 + g * 8;

    // prefetch first K tile (64 keys = 4 fragments)
    short8 kreg[4];
#pragma unroll
    for (int n = 0; n < 4; n++)
        kreg[n] = *(const short8*)(kb_base + (size_t)(n * 16) * 768);

    // preload first V tile (current buffer); vnxt holds the tile in flight
    short8 vreg[2][2], vnxt[2][2];
#pragma unroll
    for (int kk = 0; kk < 2; kk++) {
        vreg[kk][0] = *(const short8*)(vp0 + kk * 32);
        vreg[kk][1] = *(const short8*)(vp1 + kk * 32);
    }

    for (int kv = 0; kv < SEQ; kv += 64) {
        // ---- issue NEXT tile's V loads (in flight across the whole body)
        if (kv + 64 < SEQ) {
#pragma unroll
            for (int kk = 0; kk < 2; kk++) {
                vnxt[kk][0] = *(const short8*)(vp0 + kv + 64 + kk * 32);
                vnxt[kk][1] = *(const short8*)(vp1 + kv + 64 + kk * 32);
            }
        }

        // ---- scores (log2 domain): s[n][m][j] = S[key=n*16+g*4+j][q=m*16+fr]
        f32x4 s[4][2];
#pragma unroll
        for (int n = 0; n < 4; n++)
#pragma unroll
            for (int m = 0; m < 2; m++)
                s[n][m] = __builtin_amdgcn_mfma_f32_16x16x32_bf16(kreg[n], qb[m],
                                                                  fz, 0, 0, 0);

        // ---- prefetch next K tile (completes during exp + PV)
        if (kv + 64 < SEQ) {
#pragma unroll
            for (int n = 0; n < 4; n++)
                kreg[n] = *(const short8*)(kb_base +
                                           (size_t)(kv + 64 + n * 16) * 768);
        }

        // ---- P = exp2(s), pack to bf16 in-lane, PV + ones-column row-sum
#pragma unroll
        for (int kk = 0; kk < 2; kk++) {
#pragma unroll
            for (int m = 0; m < 2; m++) {
                float p0 = exp2_fast(s[2 * kk][m][0]);
                float p1 = exp2_fast(s[2 * kk][m][1]);
                float p2 = exp2_fast(s[2 * kk][m][2]);
                float p3 = exp2_fast(s[2 * kk][m][3]);
                float p4 = exp2_fast(s[2 * kk + 1][m][0]);
                float p5 = exp2_fast(s[2 * kk + 1][m][1]);
                float p6 = exp2_fast(s[2 * kk + 1][m][2]);
                float p7 = exp2_fast(s[2 * kk + 1][m][3]);
                union { short8 s8; uint32_t u[4]; } pa;
                asm("v_cvt_pk_bf16_f32 %0, %1, %2"
                    : "=v"(pa.u[0]) : "v"(p0), "v"(p1));
                asm("v_cvt_pk_bf16_f32 %0, %1, %2"
                    : "=v"(pa.u[1]) : "v"(p2), "v"(p3));
                asm("v_cvt_pk_bf16_f32 %0, %1, %2"
                    : "=v"(pa.u[2]) : "v"(p4), "v"(p5));
                asm("v_cvt_pk_bf16_f32 %0, %1, %2"
                    : "=v"(pa.u[3]) : "v"(p6), "v"(p7));
                acc[m][0] = __builtin_amdgcn_mfma_f32_16x16x32_bf16(
                    pa.s8, vreg[kk][0], acc[m][0], 0, 0, 0);
                acc[m][1] = __builtin_amdgcn_mfma_f32_16x16x32_bf16(
                    pa.s8, vreg[kk][1], acc[m][1], 0, 0, 0);
                asum[m] = __builtin_amdgcn_mfma_f32_16x16x32_bf16(
                    pa.s8, ones8, asum[m], 0, 0, 0);
            }
        }

        // ---- rotate: consumed vreg <- in-flight vnxt (static indices only)
        if (kv + 64 < SEQ) {
#pragma unroll
            for (int kk = 0; kk < 2; kk++) {
                vreg[kk][0] = vnxt[kk][0];
                vreg[kk][1] = vnxt[kk][1];
            }
        }
    }

    // ---- epilogue: lane (fr,g) holds ctx[q=m*16+g*4+j][hd=n*16+fr];
    //      asum[m][j] is the matching row sum (same D layout) -> no shfl.
#pragma unroll
    for (int m = 0; m < 2; m++)
#pragma unroll
        for (int j = 0; j < 4; j++) {
            float inv = 1.f / asum[m][j];
#pragma unroll
            for (int n = 0; n < 2; n++) {
                size_t row = (size_t)b * SEQ + q0 + m * 16 + g * 4 + j;
                ctx[row * 256 + h * 32 + n * 16 + fr] =
                    f2bf(acc[m][n][j] * inv);
            }
        }
}

// ---------------------------------------------------------------------------
extern "C" void kernel_launch(void* const* d_in, const int* in_sizes, int n_in,
                              void* d_out, int out_size, void* d_ws,
                              size_t ws_size, hipStream_t stream) {
    const float* x   = (const float*)d_in[0];
    const float* wq  = (const float*)d_in[1];
    const float* wk  = (const float*)d_in[2];
    const float* wv  = (const float*)d_in[3];
    const float* g1  = (const float*)d_in[4];
    const float* be1 = (const float*)d_in[5];
    const float* g2  = (const float*)d_in[6];
    const float* be2 = (const float*)d_in[7];
    const float* wf1 = (const float*)d_in[8];
    const float* bf1 = (const float*)d_in[9];
    const float* wf2 = (const float*)d_in[10];
    const float* bf2 = (const float*)d_in[11];

    char* ws = (char*)d_ws;
    const size_t SZ16M = (size_t)ROWS * 256 * 2;  // 16 MiB
    ushort_t* wqkvT = (ushort_t*)(ws);                      // 768*256*2
    ushort_t* wf1T  = (ushort_t*)(ws + 393216);
    ushort_t* wf2T  = (ushort_t*)(ws + 524288);
    ushort_t* xn    = (ushort_t*)(ws + 655360);             // 16 MiB (reused as h)
    ushort_t* qkvb  = (ushort_t*)(ws + 655360 + SZ16M);     // 48 MiB
    ushort_t* vtb   = (ushort_t*)(ws + 655360 + SZ16M + (size_t)ROWS * 768 * 2);
    ushort_t* ctxb  = (ushort_t*)((char*)vtb + SZ16M);
    ushort_t* ab    = (ushort_t*)((char*)ctxb + SZ16M);
    ushort_t* hb    = xn;  // xn dead after QKV GEMM

    prep_weights<<<dim3(1280), dim3(256), 0, stream>>>(wq, wk, wv, wf1, wf2,
                                                       wqkvT, wf1T, wf2T);
    ln_kernel<0><<<dim3(ROWS / 4), dim3(256), 0, stream>>>(x, nullptr, g1, be1,
                                                           xn);
    gemm_bt<3><<<dim3(256 * 6), dim3(256), 0, stream>>>(
        xn, wqkvT, (void*)qkvb, nullptr, nullptr, vtb, 6, 768);
    attn_kernel<<<dim3(2048), dim3(256), 0, stream>>>(qkvb, vtb, ctxb);
    ln_kernel<1><<<dim3(ROWS / 4), dim3(256), 0, stream>>>(x, ctxb, g2, be2, ab);
    gemm_bt<1><<<dim3(256 * 2), dim3(256), 0, stream>>>(
        ab, wf1T, (void*)hb, bf1, nullptr, nullptr, 2, 256);
    gemm_bt<2><<<dim3(256 * 2), dim3(256), 0, stream>>>(
        hb, wf2T, d_out, bf2, ab, nullptr, 2, 256);
}

// Round 11
// 194.023 us; speedup vs baseline: 1.2394x; 1.0028x over previous
//
#include <hip/hip_runtime.h>
#include <stdint.h>

typedef unsigned short ushort_t;
typedef __attribute__((ext_vector_type(8))) short short8;
typedef __attribute__((ext_vector_type(4))) float f32x4;
typedef __attribute__((ext_vector_type(4))) unsigned short ushort4v;

#define NBATCH 32
#define SEQ 1024
#define DIM 256
#define NH 8
#define ROWS (NBATCH * SEQ)   // 32768

__device__ __forceinline__ ushort_t f2bf(float f) {
    uint32_t u = __float_as_uint(f);
    u += 0x7fffu + ((u >> 16) & 1u);   // round-to-nearest-even
    return (ushort_t)(u >> 16);
}
__device__ __forceinline__ float bf2f(ushort_t h) {
    return __uint_as_float(((uint32_t)h) << 16);
}
__device__ __forceinline__ float exp2_fast(float x) {
    float r;
    asm("v_exp_f32 %0, %1" : "=v"(r) : "v"(x));
    return r;
}

typedef __attribute__((address_space(3))) void lds_void_t;
typedef const __attribute__((address_space(1))) void glob_void_t;
__device__ __forceinline__ void gld_lds16(const void* g, void* l) {
    __builtin_amdgcn_global_load_lds((glob_void_t*)g, (lds_void_t*)l, 16, 0, 0);
}

// ---------------------------------------------------------------------------
// Kernel 1: weight prep — wT[n][k] = (bf16) w[k][n] for wq|wk|wv packed, wf1, wf2
// wq additionally scaled by log2(e): attention softmax runs in exp2 domain.
// ---------------------------------------------------------------------------
__global__ __launch_bounds__(256) void prep_weights(
    const float* __restrict__ wq, const float* __restrict__ wk,
    const float* __restrict__ wv, const float* __restrict__ wf1,
    const float* __restrict__ wf2, ushort_t* __restrict__ wqkvT,
    ushort_t* __restrict__ wf1T, ushort_t* __restrict__ wf2T) {
    int n = blockIdx.x;
    int k = threadIdx.x;
    if (n < 768) {
        const float* w = (n < 256) ? wq : (n < 512 ? wk : wv);
        int nn = n & 255;
        float v = w[k * 256 + nn];
        if (n < 256) v *= 1.4426950408889634f;  // log2(e) fold for exp2 softmax
        wqkvT[n * 256 + k] = f2bf(v);
    } else if (n < 1024) {
        int nn = n - 768;
        wf1T[nn * 256 + k] = f2bf(wf1[k * 256 + nn]);
    } else {
        int nn = n - 1024;
        wf2T[nn * 256 + k] = f2bf(wf2[k * 256 + nn]);
    }
}

// ---------------------------------------------------------------------------
// Kernel 2/6: LayerNorm (one wave per 256-elem row), optional +ctx residual
// ---------------------------------------------------------------------------
template <int ADD_CTX>
__global__ __launch_bounds__(256) void ln_kernel(
    const float* __restrict__ x, const ushort_t* __restrict__ ctx,
    const float* __restrict__ g, const float* __restrict__ beta,
    ushort_t* __restrict__ out) {
    int wid = threadIdx.x >> 6, lane = threadIdx.x & 63;
    size_t row = (size_t)blockIdx.x * 4 + wid;
    size_t base = row * 256 + lane * 4;
    float4 v = *(const float4*)(x + base);
    if (ADD_CTX) {
        ushort4v c = *(const ushort4v*)(ctx + base);
        v.x += bf2f(c[0]); v.y += bf2f(c[1]);
        v.z += bf2f(c[2]); v.w += bf2f(c[3]);
    }
    float s  = v.x + v.y + v.z + v.w;
    float s2 = v.x * v.x + v.y * v.y + v.z * v.z + v.w * v.w;
#pragma unroll
    for (int msk = 1; msk < 64; msk <<= 1) {
        s  += __shfl_xor(s, msk);
        s2 += __shfl_xor(s2, msk);
    }
    float mu  = s * (1.f / 256.f);
    float var = s2 * (1.f / 256.f) - mu * mu;
    float rs  = rsqrtf(var + 1e-5f);
    const float4 gv = *(const float4*)(g + lane * 4);
    const float4 bv = *(const float4*)(beta + lane * 4);
    ushort4v o;
    o[0] = f2bf((v.x - mu) * rs * gv.x + bv.x);
    o[1] = f2bf((v.y - mu) * rs * gv.y + bv.y);
    o[2] = f2bf((v.z - mu) * rs * gv.z + bv.z);
    o[3] = f2bf((v.w - mu) * rs * gv.w + bv.w);
    *(ushort4v*)(out + base) = o;
}

// ---------------------------------------------------------------------------
// Kernels 3/7/8: GEMM C[M x N] = A[M x 256] @ B^T[N x 256]^T   (bf16, fp32 acc)
// XCD-aware block swizzle (grid % 8 == 0 for all call sites).
// EPI: 0 = plain -> bf16 C
//      1 = +bias, relu -> bf16 (FFN1)
//      2 = +bias, +res -> f32  (FFN2 -> d_out)
//      3 = QKV + fused V-relayout: cols<512 -> qkv bf16; cols>=512 -> packed
//          ushort4 store into vt[bh][hd][slot] with slot = sigma(key)
//          (sigma = inverse of attn's PV slot permutation pi; j=0..3 keys map
//           to consecutive slots since key base is 0 mod 4).
// ---------------------------------------------------------------------------
template <int EPI>
__global__ __launch_bounds__(256) void gemm_bt(
    const ushort_t* __restrict__ A, const ushort_t* __restrict__ B,
    void* __restrict__ Cp, const float* __restrict__ bias,
    const ushort_t* __restrict__ res, ushort_t* __restrict__ vtout, int nbn,
    int ldc) {
    __shared__ ushort_t lds_a[4096];  // [128][32]
    __shared__ ushort_t lds_b[4096];  // [128][32] (rows = output cols)
    int cpx = gridDim.x >> 3;
    int blk = (blockIdx.x & 7) * cpx + (blockIdx.x >> 3);
    int bn = blk % nbn, bm = blk / nbn;
    int m0 = bm * 128, n0 = bn * 128;
    int tid = threadIdx.x, wid = tid >> 6, lane = tid & 63;
    int fr = lane & 15, g = lane >> 4;
    int wm = (wid >> 1) * 64, wn = (wid & 1) * 64;

    f32x4 acc[4][4];
    const f32x4 fz = {0.f, 0.f, 0.f, 0.f};
#pragma unroll
    for (int m = 0; m < 4; m++)
#pragma unroll
        for (int n = 0; n < 4; n++) acc[m][n] = fz;

    for (int kt = 0; kt < 256; kt += 32) {
#pragma unroll
        for (int i = 0; i < 2; i++) {
            const ushort_t* as =
                A + (size_t)(m0 + i * 64 + (tid >> 2)) * 256 + kt + (tid & 3) * 8;
            gld_lds16(as, &lds_a[i * 2048 + wid * 512]);
            const ushort_t* bs =
                B + (size_t)(n0 + i * 64 + (tid >> 2)) * 256 + kt + (tid & 3) * 8;
            gld_lds16(bs, &lds_b[i * 2048 + wid * 512]);
        }
        __syncthreads();
        short8 af[4], bfr[4];
#pragma unroll
        for (int m = 0; m < 4; m++)
            af[m] = *(const short8*)&lds_a[(wm + m * 16 + fr) * 32 + g * 8];
#pragma unroll
        for (int n = 0; n < 4; n++)
            bfr[n] = *(const short8*)&lds_b[(wn + n * 16 + fr) * 32 + g * 8];
#pragma unroll
        for (int m = 0; m < 4; m++)
#pragma unroll
            for (int n = 0; n < 4; n++)
                acc[m][n] = __builtin_amdgcn_mfma_f32_16x16x32_bf16(
                    af[m], bfr[n], acc[m][n], 0, 0, 0);
        __syncthreads();
    }

#pragma unroll
    for (int m = 0; m < 4; m++)
#pragma unroll
        for (int n = 0; n < 4; n++) {
            int col = n0 + wn + n * 16 + fr;
            if (EPI == 3 && col >= 512) {
                // V column: fused transpose+permute relayout into vt.
                int hd = col & 31;
                int hh = (col >> 5) & 7;  // head
                int rowbase = m0 + wm + m * 16 + g * 4;
                int bb = rowbase >> 10;
                int key = rowbase & 1023;  // key base, multiple of 4
                int slot0 = (key & ~31) + (((key & 15) >> 2) << 3) +
                            (((key >> 4) & 1) << 2);
                ushort4v o;
                o[0] = f2bf(acc[m][n][0]);
                o[1] = f2bf(acc[m][n][1]);
                o[2] = f2bf(acc[m][n][2]);
                o[3] = f2bf(acc[m][n][3]);
                *(ushort4v*)(vtout + (size_t)(bb * 8 + hh) * 32768 +
                             (size_t)hd * 1024 + slot0) = o;
            } else {
                float bv = (EPI == 1 || EPI == 2) ? bias[col] : 0.f;
#pragma unroll
                for (int j = 0; j < 4; j++) {
                    size_t row = (size_t)(m0 + wm + m * 16 + g * 4 + j);
                    float v = acc[m][n][j] + bv;
                    if (EPI == 1) v = fmaxf(v, 0.f);
                    if (EPI == 2) {
                        v += bf2f(res[row * 256 + col]);
                        ((float*)Cp)[row * ldc + col] = v;
                    } else {
                        ((ushort_t*)Cp)[row * ldc + col] = f2bf(v);
                    }
                }
            }
        }
}

// ---------------------------------------------------------------------------
// Kernel 5: flash attention, swapped-QK^T, zero LDS, branch-free & shfl-free.
// R5 structure + ONE change: the packed P is software-pipelined one tile
// forward (pP carried in registers). Body = QK_t -> issue K_{t+1} ->
// PV_{t-1}(pP,vreg) -> issue V_t -> EXP_t->pP. PV no longer depends on this
// iteration's exp2, so the QK+PV MFMA cluster and the exp2 VALU stream are
// independent and can interleave. All buffers stay single-buffered with
// issue-after-use (no bumped pointers / named A-B dbufs / rotates — the
// R6-R8 poisoned patterns). Accumulation order per tile unchanged.
// ---------------------------------------------------------------------------
__global__ __launch_bounds__(256, 4) void attn_kernel(
    const ushort_t* __restrict__ qkv, const ushort_t* __restrict__ vt,
    ushort_t* __restrict__ ctx) {
    int cpx = gridDim.x >> 3;
    int wgid = (blockIdx.x & 7) * cpx + (blockIdx.x >> 3);
    int bh = wgid >> 3, qt = wgid & 7;
    int b = bh >> 3, h = bh & 7;
    int tid = threadIdx.x, wid = tid >> 6, lane = tid & 63;
    int fr = lane & 15, g = lane >> 4;
    int q0 = qt * 128 + wid * 32;
    const ushort_t* qbase = qkv + (size_t)b * SEQ * 768;
    const ushort_t* vbase = vt + (size_t)bh * 32768;

    // Q fragments (B operand of swapped QK^T); Q pre-scaled by log2(e)
    short8 qb[2];
#pragma unroll
    for (int m = 0; m < 2; m++)
        qb[m] = *(const short8*)(qbase + (size_t)(q0 + m * 16 + fr) * 768 +
                                 h * 32 + g * 8);

    f32x4 acc[2][2], asum[2];
    const f32x4 fz = {0.f, 0.f, 0.f, 0.f};
#pragma unroll
    for (int m = 0; m < 2; m++) {
        acc[m][0] = fz;
        acc[m][1] = fz;
        asum[m] = fz;
    }
    // all-ones bf16 B-fragment for the row-sum MFMA
    short8 ones8;
#pragma unroll
    for (int i = 0; i < 8; i++) ones8[i] = (short)0x3f80;

    // per-lane K base (row = kv + n*16 + fr), V bases (rows fr and 16+fr)
    const ushort_t* kb_base = qbase + 256 + h * 32 + g * 8 + (size_t)fr * 768;
    const ushort_t* vp0 = vbase + (size_t)fr * 1024 + g * 8;
    const ushort_t* vp1 = vbase + (size_t)(16 + fr) * 1024 + g * 8;

    // preload K tile 0 and V tile 0
    short8 kreg[4];
#pragma unroll
    for (int n = 0; n < 4; n++)
        kreg[n] = *(const short8*)(kb_base + (size_t)(n * 16) * 768);
    short8 vreg[2][2];
#pragma unroll
    for (int kk = 0; kk < 2; kk++) {
        vreg[kk][0] = *(const short8*)(vp0 + kk * 32);
        vreg[kk][1] = *(const short8*)(vp1 + kk * 32);
    }

    short8 pP[2][2];  // packed P for the previous tile (pipelined operand)

    // ---- peel tile 0: QK + issue K_1 + EXP -> pP (its PV runs in iter 1)
    {
        f32x4 s[4][2];
#pragma unroll
        for (int n = 0; n < 4; n++)
#pragma unroll
            for (int m = 0; m < 2; m++)
                s[n][m] = __builtin_amdgcn_mfma_f32_16x16x32_bf16(kreg[n], qb[m],
                                                                  fz, 0, 0, 0);
#pragma unroll
        for (int n = 0; n < 4; n++)
            kreg[n] = *(const short8*)(kb_base + (size_t)(64 + n * 16) * 768);
#pragma unroll
        for (int kk = 0; kk < 2; kk++)
#pragma unroll
            for (int m = 0; m < 2; m++) {
                float p0 = exp2_fast(s[2 * kk][m][0]);
                float p1 = exp2_fast(s[2 * kk][m][1]);
                float p2 = exp2_fast(s[2 * kk][m][2]);
                float p3 = exp2_fast(s[2 * kk][m][3]);
                float p4 = exp2_fast(s[2 * kk + 1][m][0]);
                float p5 = exp2_fast(s[2 * kk + 1][m][1]);
                float p6 = exp2_fast(s[2 * kk + 1][m][2]);
                float p7 = exp2_fast(s[2 * kk + 1][m][3]);
                union { short8 s8; uint32_t u[4]; } pa;
                asm("v_cvt_pk_bf16_f32 %0, %1, %2"
                    : "=v"(pa.u[0]) : "v"(p0), "v"(p1));
                asm("v_cvt_pk_bf16_f32 %0, %1, %2"
                    : "=v"(pa.u[1]) : "v"(p2), "v"(p3));
                asm("v_cvt_pk_bf16_f32 %0, %1, %2"
                    : "=v"(pa.u[2]) : "v"(p4), "v"(p5));
                asm("v_cvt_pk_bf16_f32 %0, %1, %2"
                    : "=v"(pa.u[3]) : "v"(p6), "v"(p7));
                pP[kk][m] = pa.s8;
            }
    }

    // ---- main loop: iter for tile t computes QK_t and PV_{t-1}
    for (int kv = 64; kv < SEQ; kv += 64) {
        // QK_t (kreg = K tile t, prefetched last iteration)
        f32x4 s[4][2];
#pragma unroll
        for (int n = 0; n < 4; n++)
#pragma unroll
            for (int m = 0; m < 2; m++)
                s[n][m] = __builtin_amdgcn_mfma_f32_16x16x32_bf16(kreg[n], qb[m],
                                                                  fz, 0, 0, 0);

        // issue K_{t+1} (kreg consumed above; full-body load-use distance)
        if (kv + 64 < SEQ) {
#pragma unroll
            for (int n = 0; n < 4; n++)
                kreg[n] = *(const short8*)(kb_base +
                                           (size_t)(kv + 64 + n * 16) * 768);
        }

        // PV_{t-1}: pP packed a full iteration ago, vreg loaded last iter
#pragma unroll
        for (int kk = 0; kk < 2; kk++)
#pragma unroll
            for (int m = 0; m < 2; m++) {
                acc[m][0] = __builtin_amdgcn_mfma_f32_16x16x32_bf16(
                    pP[kk][m], vreg[kk][0], acc[m][0], 0, 0, 0);
                acc[m][1] = __builtin_amdgcn_mfma_f32_16x16x32_bf16(
                    pP[kk][m], vreg[kk][1], acc[m][1], 0, 0, 0);
                asum[m] = __builtin_amdgcn_mfma_f32_16x16x32_bf16(
                    pP[kk][m], ones8, asum[m], 0, 0, 0);
            }

        // issue V_t (vreg consumed above; used by PV_t next iteration)
#pragma unroll
        for (int kk = 0; kk < 2; kk++) {
            vreg[kk][0] = *(const short8*)(vp0 + kv + kk * 32);
            vreg[kk][1] = *(const short8*)(vp1 + kv + kk * 32);
        }

        // EXP_t: pP <- packed exp2(s) (consumed by PV_t next iteration)
#pragma unroll
        for (int kk = 0; kk < 2; kk++)
#pragma unroll
            for (int m = 0; m < 2; m++) {
                float p0 = exp2_fast(s[2 * kk][m][0]);
                float p1 = exp2_fast(s[2 * kk][m][1]);
                float p2 = exp2_fast(s[2 * kk][m][2]);
                float p3 = exp2_fast(s[2 * kk][m][3]);
                float p4 = exp2_fast(s[2 * kk + 1][m][0]);
                float p5 = exp2_fast(s[2 * kk + 1][m][1]);
                float p6 = exp2_fast(s[2 * kk + 1][m][2]);
                float p7 = exp2_fast(s[2 * kk + 1][m][3]);
                union { short8 s8; uint32_t u[4]; } pa;
                asm("v_cvt_pk_bf16_f32 %0, %1, %2"
                    : "=v"(pa.u[0]) : "v"(p0), "v"(p1));
                asm("v_cvt_pk_bf16_f32 %0, %1, %2"
                    : "=v"(pa.u[1]) : "v"(p2), "v"(p3));
                asm("v_cvt_pk_bf16_f32 %0, %1, %2"
                    : "=v"(pa.u[2]) : "v"(p4), "v"(p5));
                asm("v_cvt_pk_bf16_f32 %0, %1, %2"
                    : "=v"(pa.u[3]) : "v"(p6), "v"(p7));
                pP[kk][m] = pa.s8;
            }
    }

    // ---- drain: PV for the last tile (15)
#pragma unroll
    for (int kk = 0; kk < 2; kk++)
#pragma unroll
        for (int m = 0; m < 2; m++) {
            acc[m][0] = __builtin_amdgcn_mfma_f32_16x16x32_bf16(
                pP[kk][m], vreg[kk][0], acc[m][0], 0, 0, 0);
            acc[m][1] = __builtin_amdgcn_mfma_f32_16x16x32_bf16(
                pP[kk][m], vreg[kk][1], acc[m][1], 0, 0, 0);
            asum[m] = __builtin_amdgcn_mfma_f32_16x16x32_bf16(
                pP[kk][m], ones8, asum[m], 0, 0, 0);
        }

    // ---- epilogue: lane (fr,g) holds ctx[q=m*16+g*4+j][hd=n*16+fr];
    //      asum[m][j] is the matching row sum (same D layout) -> no shfl.
#pragma unroll
    for (int m = 0; m < 2; m++)
#pragma unroll
        for (int j = 0; j < 4; j++) {
            float inv = 1.f / asum[m][j];
#pragma unroll
            for (int n = 0; n < 2; n++) {
                size_t row = (size_t)b * SEQ + q0 + m * 16 + g * 4 + j;
                ctx[row * 256 + h * 32 + n * 16 + fr] =
                    f2bf(acc[m][n][j] * inv);
            }
        }
}

// ---------------------------------------------------------------------------
extern "C" void kernel_launch(void* const* d_in, const int* in_sizes, int n_in,
                              void* d_out, int out_size, void* d_ws,
                              size_t ws_size, hipStream_t stream) {
    const float* x   = (const float*)d_in[0];
    const float* wq  = (const float*)d_in[1];
    const float* wk  = (const float*)d_in[2];
    const float* wv  = (const float*)d_in[3];
    const float* g1  = (const float*)d_in[4];
    const float* be1 = (const float*)d_in[5];
    const float* g2  = (const float*)d_in[6];
    const float* be2 = (const float*)d_in[7];
    const float* wf1 = (const float*)d_in[8];
    const float* bf1 = (const float*)d_in[9];
    const float* wf2 = (const float*)d_in[10];
    const float* bf2 = (const float*)d_in[11];

    char* ws = (char*)d_ws;
    const size_t SZ16M = (size_t)ROWS * 256 * 2;  // 16 MiB
    ushort_t* wqkvT = (ushort_t*)(ws);                      // 768*256*2
    ushort_t* wf1T  = (ushort_t*)(ws + 393216);
    ushort_t* wf2T  = (ushort_t*)(ws + 524288);
    ushort_t* xn    = (ushort_t*)(ws + 655360);             // 16 MiB (reused as h)
    ushort_t* qkvb  = (ushort_t*)(ws + 655360 + SZ16M);     // 48 MiB
    ushort_t* vtb   = (ushort_t*)(ws + 655360 + SZ16M + (size_t)ROWS * 768 * 2);
    ushort_t* ctxb  = (ushort_t*)((char*)vtb + SZ16M);
    ushort_t* ab    = (ushort_t*)((char*)ctxb + SZ16M);
    ushort_t* hb    = xn;  // xn dead after QKV GEMM

    prep_weights<<<dim3(1280), dim3(256), 0, stream>>>(wq, wk, wv, wf1, wf2,
                                                       wqkvT, wf1T, wf2T);
    ln_kernel<0><<<dim3(ROWS / 4), dim3(256), 0, stream>>>(x, nullptr, g1, be1,
                                                           xn);
    gemm_bt<3><<<dim3(256 * 6), dim3(256), 0, stream>>>(
        xn, wqkvT, (void*)qkvb, nullptr, nullptr, vtb, 6, 768);
    attn_kernel<<<dim3(2048), dim3(256), 0, stream>>>(qkvb, vtb, ctxb);
    ln_kernel<1><<<dim3(ROWS / 4), dim3(256), 0, stream>>>(x, ctxb, g2, be2, ab);
    gemm_bt<1><<<dim3(256 * 2), dim3(256), 0, stream>>>(
        ab, wf1T, (void*)hb, bf1, nullptr, nullptr, 2, 256);
    gemm_bt<2><<<dim3(256 * 2), dim3(256), 0, stream>>>(
        hb, wf2T, d_out, bf2, ab, nullptr, 2, 256);
}

// Round 13
// 126.441 us; speedup vs baseline: 1.9019x; 1.5345x over previous
//
#include <hip/hip_runtime.h>
#include <stdint.h>

typedef unsigned short ushort_t;
typedef __attribute__((ext_vector_type(8))) short short8;
typedef __attribute__((ext_vector_type(4))) float f32x4;
typedef __attribute__((ext_vector_type(4))) unsigned short ushort4v;

#define NBATCH 32
#define SEQ 1024
#define DIM 256
#define NH 8
#define ROWS (NBATCH * SEQ)   // 32768

__device__ __forceinline__ ushort_t f2bf(float f) {
    uint32_t u = __float_as_uint(f);
    u += 0x7fffu + ((u >> 16) & 1u);   // round-to-nearest-even
    return (ushort_t)(u >> 16);
}
__device__ __forceinline__ float bf2f(ushort_t h) {
    return __uint_as_float(((uint32_t)h) << 16);
}
__device__ __forceinline__ float exp2_fast(float x) {
    float r;
    asm("v_exp_f32 %0, %1" : "=v"(r) : "v"(x));
    return r;
}

typedef __attribute__((address_space(3))) void lds_void_t;
typedef const __attribute__((address_space(1))) void glob_void_t;
__device__ __forceinline__ void gld_lds16(const void* g, void* l) {
    __builtin_amdgcn_global_load_lds((glob_void_t*)g, (lds_void_t*)l, 16, 0, 0);
}

// ---------------------------------------------------------------------------
// Kernel 1: weight prep — wT[n][k] = (bf16) w[k][n] for wq|wk|wv packed, wf1, wf2
// wq additionally scaled by log2(e): attention softmax runs in exp2 domain.
// ---------------------------------------------------------------------------
__global__ __launch_bounds__(256) void prep_weights(
    const float* __restrict__ wq, const float* __restrict__ wk,
    const float* __restrict__ wv, const float* __restrict__ wf1,
    const float* __restrict__ wf2, ushort_t* __restrict__ wqkvT,
    ushort_t* __restrict__ wf1T, ushort_t* __restrict__ wf2T) {
    int n = blockIdx.x;
    int k = threadIdx.x;
    if (n < 768) {
        const float* w = (n < 256) ? wq : (n < 512 ? wk : wv);
        int nn = n & 255;
        float v = w[k * 256 + nn];
        if (n < 256) v *= 1.4426950408889634f;  // log2(e) fold for exp2 softmax
        wqkvT[n * 256 + k] = f2bf(v);
    } else if (n < 1024) {
        int nn = n - 768;
        wf1T[nn * 256 + k] = f2bf(wf1[k * 256 + nn]);
    } else {
        int nn = n - 1024;
        wf2T[nn * 256 + k] = f2bf(wf2[k * 256 + nn]);
    }
}

// ---------------------------------------------------------------------------
// Kernel 2/6: LayerNorm (one wave per 256-elem row), optional +ctx residual
// ---------------------------------------------------------------------------
template <int ADD_CTX>
__global__ __launch_bounds__(256) void ln_kernel(
    const float* __restrict__ x, const ushort_t* __restrict__ ctx,
    const float* __restrict__ g, const float* __restrict__ beta,
    ushort_t* __restrict__ out) {
    int wid = threadIdx.x >> 6, lane = threadIdx.x & 63;
    size_t row = (size_t)blockIdx.x * 4 + wid;
    size_t base = row * 256 + lane * 4;
    float4 v = *(const float4*)(x + base);
    if (ADD_CTX) {
        ushort4v c = *(const ushort4v*)(ctx + base);
        v.x += bf2f(c[0]); v.y += bf2f(c[1]);
        v.z += bf2f(c[2]); v.w += bf2f(c[3]);
    }
    float s  = v.x + v.y + v.z + v.w;
    float s2 = v.x * v.x + v.y * v.y + v.z * v.z + v.w * v.w;
#pragma unroll
    for (int msk = 1; msk < 64; msk <<= 1) {
        s  += __shfl_xor(s, msk);
        s2 += __shfl_xor(s2, msk);
    }
    float mu  = s * (1.f / 256.f);
    float var = s2 * (1.f / 256.f) - mu * mu;
    float rs  = rsqrtf(var + 1e-5f);
    const float4 gv = *(const float4*)(g + lane * 4);
    const float4 bv = *(const float4*)(beta + lane * 4);
    ushort4v o;
    o[0] = f2bf((v.x - mu) * rs * gv.x + bv.x);
    o[1] = f2bf((v.y - mu) * rs * gv.y + bv.y);
    o[2] = f2bf((v.z - mu) * rs * gv.z + bv.z);
    o[3] = f2bf((v.w - mu) * rs * gv.w + bv.w);
    *(ushort4v*)(out + base) = o;
}

// ---------------------------------------------------------------------------
// Kernels 3/7/8: GEMM C[M x N] = A[M x 256] @ B^T[N x 256]^T   (bf16, fp32 acc)
// XCD-aware block swizzle (grid % 8 == 0 for all call sites).
// EPI: 0 = plain -> bf16 C
//      1 = +bias, relu -> bf16 (FFN1)
//      2 = +bias, +res -> f32  (FFN2 -> d_out)
//      3 = QKV with fragment-packed K/V epilogue:
//          cols<256   -> Q bf16 into Cp (ldc=256)
//          256..511   -> kpk[bh][t16][lane]: lane (fr=key&15, g=hd>>3) holds
//                        K[key][hd=g*8..+7] -> attn K-loads become one
//                        contiguous 1KB segment per instruction.
//          >=512      -> vpk[bh][t64][frag=kk*2+nn][lane]: sigma-permuted V
//                        fragments; attn V-loads likewise coalesced.
// ---------------------------------------------------------------------------
template <int EPI>
__global__ __launch_bounds__(256) void gemm_bt(
    const ushort_t* __restrict__ A, const ushort_t* __restrict__ B,
    void* __restrict__ Cp, const float* __restrict__ bias,
    const ushort_t* __restrict__ res, ushort_t* __restrict__ kout,
    ushort_t* __restrict__ vout, int nbn, int ldc) {
    __shared__ ushort_t lds_a[4096];  // [128][32]
    __shared__ ushort_t lds_b[4096];  // [128][32] (rows = output cols)
    int cpx = gridDim.x >> 3;
    int blk = (blockIdx.x & 7) * cpx + (blockIdx.x >> 3);
    int bn = blk % nbn, bm = blk / nbn;
    int m0 = bm * 128, n0 = bn * 128;
    int tid = threadIdx.x, wid = tid >> 6, lane = tid & 63;
    int fr = lane & 15, g = lane >> 4;
    int wm = (wid >> 1) * 64, wn = (wid & 1) * 64;

    f32x4 acc[4][4];
    const f32x4 fz = {0.f, 0.f, 0.f, 0.f};
#pragma unroll
    for (int m = 0; m < 4; m++)
#pragma unroll
        for (int n = 0; n < 4; n++) acc[m][n] = fz;

    for (int kt = 0; kt < 256; kt += 32) {
#pragma unroll
        for (int i = 0; i < 2; i++) {
            const ushort_t* as =
                A + (size_t)(m0 + i * 64 + (tid >> 2)) * 256 + kt + (tid & 3) * 8;
            gld_lds16(as, &lds_a[i * 2048 + wid * 512]);
            const ushort_t* bs =
                B + (size_t)(n0 + i * 64 + (tid >> 2)) * 256 + kt + (tid & 3) * 8;
            gld_lds16(bs, &lds_b[i * 2048 + wid * 512]);
        }
        __syncthreads();
        short8 af[4], bfr[4];
#pragma unroll
        for (int m = 0; m < 4; m++)
            af[m] = *(const short8*)&lds_a[(wm + m * 16 + fr) * 32 + g * 8];
#pragma unroll
        for (int n = 0; n < 4; n++)
            bfr[n] = *(const short8*)&lds_b[(wn + n * 16 + fr) * 32 + g * 8];
#pragma unroll
        for (int m = 0; m < 4; m++)
#pragma unroll
            for (int n = 0; n < 4; n++)
                acc[m][n] = __builtin_amdgcn_mfma_f32_16x16x32_bf16(
                    af[m], bfr[n], acc[m][n], 0, 0, 0);
        __syncthreads();
    }

#pragma unroll
    for (int m = 0; m < 4; m++)
#pragma unroll
        for (int n = 0; n < 4; n++) {
            int col = n0 + wn + n * 16 + fr;
            int rowbase = m0 + wm + m * 16 + g * 4;
            if (EPI == 3 && col >= 512) {
                // V: fragment-packed, sigma-permuted (j=0..3 -> one 8B store)
                int hh = (col >> 5) & 7, hd = col & 31;
                int nn = hd >> 4, frv = hd & 15;
                int bb = rowbase >> 10;
                int key = rowbase & 1023;  // multiple of 4
                int slot0 = (key & ~31) + (((key & 15) >> 2) << 3) +
                            (((key >> 4) & 1) << 2);
                int t64 = slot0 >> 6, kk = (slot0 & 63) >> 5;
                int gv = (slot0 & 31) >> 3, e0 = slot0 & 7;
                ushort4v o;
                o[0] = f2bf(acc[m][n][0]);
                o[1] = f2bf(acc[m][n][1]);
                o[2] = f2bf(acc[m][n][2]);
                o[3] = f2bf(acc[m][n][3]);
                *(ushort4v*)(vout + (size_t)(bb * 8 + hh) * 32768 + t64 * 2048 +
                             (kk * 2 + nn) * 512 + (gv * 16 + frv) * 8 + e0) = o;
            } else if (EPI == 3 && col >= 256) {
                // K: fragment-packed scalar stores (16B apart across j)
                int hh = (col >> 5) & 7, hd = col & 31;
                int gk = hd >> 3, e = hd & 7;
                int bb = rowbase >> 10;
                int s = rowbase & 1023;  // key base; (s>>4) const across j
                size_t base = (size_t)(bb * 8 + hh) * 32768 + (s >> 4) * 512 +
                              gk * 128 + e;
#pragma unroll
                for (int j = 0; j < 4; j++)
                    kout[base + ((s & 15) + j) * 8] = f2bf(acc[m][n][j]);
            } else {
                float bv = (EPI == 1 || EPI == 2) ? bias[col] : 0.f;
#pragma unroll
                for (int j = 0; j < 4; j++) {
                    size_t row = (size_t)(rowbase + j);
                    float v = acc[m][n][j] + bv;
                    if (EPI == 1) v = fmaxf(v, 0.f);
                    if (EPI == 2) {
                        v += bf2f(res[row * 256 + col]);
                        ((float*)Cp)[row * ldc + col] = v;
                    } else {
                        ((ushort_t*)Cp)[row * ldc + col] = f2bf(v);
                    }
                }
            }
        }
}

// ---------------------------------------------------------------------------
// Kernel 5: flash attention, swapped-QK^T, zero LDS, branch-free & shfl-free.
// Loop body BYTE-IDENTICAL to R5 (4 restructures NaN'd; structure frozen).
// ONLY the load addresses changed: K/V now come from fragment-packed blobs
// (kpk/vpk), so every K/V wave-load is one contiguous 1KB segment
// (base + lane*16B) instead of 16 strided cache lines — R12 diagnosis says
// the per-CU line-transaction rate was the binder.
// ---------------------------------------------------------------------------
__global__ __launch_bounds__(256, 4) void attn_kernel(
    const ushort_t* __restrict__ q, const ushort_t* __restrict__ kpk,
    const ushort_t* __restrict__ vpk, ushort_t* __restrict__ ctx) {
    int cpx = gridDim.x >> 3;
    int wgid = (blockIdx.x & 7) * cpx + (blockIdx.x >> 3);
    int bh = wgid >> 3, qt = wgid & 7;
    int b = bh >> 3, h = bh & 7;
    int tid = threadIdx.x, wid = tid >> 6, lane = tid & 63;
    int fr = lane & 15, g = lane >> 4;
    int q0 = qt * 128 + wid * 32;
    const ushort_t* qbase = q + (size_t)b * SEQ * 256;
    const ushort_t* kpb = kpk + (size_t)bh * 32768;
    const ushort_t* vpb = vpk + (size_t)bh * 32768;
    const int l8 = lane * 8;

    // Q fragments (B operand of swapped QK^T); Q pre-scaled by log2(e)
    short8 qb[2];
#pragma unroll
    for (int m = 0; m < 2; m++)
        qb[m] = *(const short8*)(qbase + (size_t)(q0 + m * 16 + fr) * 256 +
                                 h * 32 + g * 8);

    f32x4 acc[2][2], asum[2];
    const f32x4 fz = {0.f, 0.f, 0.f, 0.f};
#pragma unroll
    for (int m = 0; m < 2; m++) {
        acc[m][0] = fz;
        acc[m][1] = fz;
        asum[m] = fz;
    }
    // all-ones bf16 B-fragment for the row-sum MFMA
    short8 ones8;
#pragma unroll
    for (int i = 0; i < 8; i++) ones8[i] = (short)0x3f80;

    // prefetch first K tile (64 keys = 4 fragments; coalesced 1KB each)
    short8 kreg[4];
#pragma unroll
    for (int n = 0; n < 4; n++)
        kreg[n] = *(const short8*)(kpb + n * 512 + l8);

    for (int kv = 0; kv < SEQ; kv += 64) {
        // ---- issue V loads for this tile (coalesced; in flight through QK)
        short8 vreg[2][2];
#pragma unroll
        for (int kk = 0; kk < 2; kk++) {
            vreg[kk][0] =
                *(const short8*)(vpb + (kv >> 6) * 2048 + (kk * 2) * 512 + l8);
            vreg[kk][1] = *(const short8*)(vpb + (kv >> 6) * 2048 +
                                           (kk * 2 + 1) * 512 + l8);
        }

        // ---- scores (log2 domain): s[n][m][j] = S[key=n*16+g*4+j][q=m*16+fr]
        f32x4 s[4][2];
#pragma unroll
        for (int n = 0; n < 4; n++)
#pragma unroll
            for (int m = 0; m < 2; m++)
                s[n][m] = __builtin_amdgcn_mfma_f32_16x16x32_bf16(kreg[n], qb[m],
                                                                  fz, 0, 0, 0);

        // ---- prefetch next K tile (completes during exp + PV)
        if (kv + 64 < SEQ) {
#pragma unroll
            for (int n = 0; n < 4; n++)
                kreg[n] = *(const short8*)(kpb + ((kv + 64) >> 4) * 512 +
                                           n * 512 + l8);
        }

        // ---- P = exp2(s), pack to bf16 in-lane, PV + ones-column row-sum
#pragma unroll
        for (int kk = 0; kk < 2; kk++) {
#pragma unroll
            for (int m = 0; m < 2; m++) {
                float p0 = exp2_fast(s[2 * kk][m][0]);
                float p1 = exp2_fast(s[2 * kk][m][1]);
                float p2 = exp2_fast(s[2 * kk][m][2]);
                float p3 = exp2_fast(s[2 * kk][m][3]);
                float p4 = exp2_fast(s[2 * kk + 1][m][0]);
                float p5 = exp2_fast(s[2 * kk + 1][m][1]);
                float p6 = exp2_fast(s[2 * kk + 1][m][2]);
                float p7 = exp2_fast(s[2 * kk + 1][m][3]);
                union { short8 s8; uint32_t u[4]; } pa;
                asm("v_cvt_pk_bf16_f32 %0, %1, %2"
                    : "=v"(pa.u[0]) : "v"(p0), "v"(p1));
                asm("v_cvt_pk_bf16_f32 %0, %1, %2"
                    : "=v"(pa.u[1]) : "v"(p2), "v"(p3));
                asm("v_cvt_pk_bf16_f32 %0, %1, %2"
                    : "=v"(pa.u[2]) : "v"(p4), "v"(p5));
                asm("v_cvt_pk_bf16_f32 %0, %1, %2"
                    : "=v"(pa.u[3]) : "v"(p6), "v"(p7));
                acc[m][0] = __builtin_amdgcn_mfma_f32_16x16x32_bf16(
                    pa.s8, vreg[kk][0], acc[m][0], 0, 0, 0);
                acc[m][1] = __builtin_amdgcn_mfma_f32_16x16x32_bf16(
                    pa.s8, vreg[kk][1], acc[m][1], 0, 0, 0);
                asum[m] = __builtin_amdgcn_mfma_f32_16x16x32_bf16(
                    pa.s8, ones8, asum[m], 0, 0, 0);
            }
        }
    }

    // ---- epilogue: lane (fr,g) holds ctx[q=m*16+g*4+j][hd=n*16+fr];
    //      asum[m][j] is the matching row sum (same D layout) -> no shfl.
#pragma unroll
    for (int m = 0; m < 2; m++)
#pragma unroll
        for (int j = 0; j < 4; j++) {
            float inv = 1.f / asum[m][j];
#pragma unroll
            for (int n = 0; n < 2; n++) {
                size_t row = (size_t)b * SEQ + q0 + m * 16 + g * 4 + j;
                ctx[row * 256 + h * 32 + n * 16 + fr] =
                    f2bf(acc[m][n][j] * inv);
            }
        }
}

// ---------------------------------------------------------------------------
extern "C" void kernel_launch(void* const* d_in, const int* in_sizes, int n_in,
                              void* d_out, int out_size, void* d_ws,
                              size_t ws_size, hipStream_t stream) {
    const float* x   = (const float*)d_in[0];
    const float* wq  = (const float*)d_in[1];
    const float* wk  = (const float*)d_in[2];
    const float* wv  = (const float*)d_in[3];
    const float* g1  = (const float*)d_in[4];
    const float* be1 = (const float*)d_in[5];
    const float* g2  = (const float*)d_in[6];
    const float* be2 = (const float*)d_in[7];
    const float* wf1 = (const float*)d_in[8];
    const float* bf1 = (const float*)d_in[9];
    const float* wf2 = (const float*)d_in[10];
    const float* bf2 = (const float*)d_in[11];

    char* ws = (char*)d_ws;
    const size_t SZ16M = (size_t)ROWS * 256 * 2;  // 16 MiB
    ushort_t* wqkvT = (ushort_t*)(ws);                      // 768*256*2
    ushort_t* wf1T  = (ushort_t*)(ws + 393216);
    ushort_t* wf2T  = (ushort_t*)(ws + 524288);
    ushort_t* xn    = (ushort_t*)(ws + 655360);             // 16 MiB (reused as h)
    ushort_t* qonly = (ushort_t*)(ws + 655360 + SZ16M);     // 16 MiB
    ushort_t* kpk   = (ushort_t*)(ws + 655360 + 2 * SZ16M); // 16 MiB
    ushort_t* vpk   = (ushort_t*)(ws + 655360 + 3 * SZ16M); // 16 MiB
    ushort_t* ctxb  = (ushort_t*)(ws + 655360 + 4 * SZ16M); // 16 MiB
    ushort_t* ab    = (ushort_t*)(ws + 655360 + 5 * SZ16M); // 16 MiB
    ushort_t* hb    = xn;  // xn dead after QKV GEMM

    prep_weights<<<dim3(1280), dim3(256), 0, stream>>>(wq, wk, wv, wf1, wf2,
                                                       wqkvT, wf1T, wf2T);
    ln_kernel<0><<<dim3(ROWS / 4), dim3(256), 0, stream>>>(x, nullptr, g1, be1,
                                                           xn);
    gemm_bt<3><<<dim3(256 * 6), dim3(256), 0, stream>>>(
        xn, wqkvT, (void*)qonly, nullptr, nullptr, kpk, vpk, 6, 256);
    attn_kernel<<<dim3(2048), dim3(256), 0, stream>>>(qonly, kpk, vpk, ctxb);
    ln_kernel<1><<<dim3(ROWS / 4), dim3(256), 0, stream>>>(x, ctxb, g2, be2, ab);
    gemm_bt<1><<<dim3(256 * 2), dim3(256), 0, stream>>>(
        ab, wf1T, (void*)hb, bf1, nullptr, nullptr, nullptr, 2, 256);
    gemm_bt<2><<<dim3(256 * 2), dim3(256), 0, stream>>>(
        hb, wf2T, d_out, bf2, ab, nullptr, nullptr, 2, 256);
}